// Round 1
// baseline (991.487 us; speedup 1.0000x reference)
//
#include <hip/hip_runtime.h>
#include <cstdint>
#include <cstddef>

#define BN_INV 0.9999950000374997f  /* 1/sqrt(1+1e-5) */

// ---------------------------------------------------------------------------
// Build per-channel 16x16 complex unitaries U[c] (interleaved re,im), exactly
// mirroring the reference: g_w = RZ(tz)*RY(ty)*H ; U = kron(g0,g1,g2,g3) with
// row permutation PTOT (CNOT ring), ty/tz pattern = [w0[c,0],w0[c,1]]*2.
// Layout: U[c*512 + r*32 + cc*2 + {0,1}]
// ---------------------------------------------------------------------------
__global__ __launch_bounds__(256) void build_U_kernel(
    const float* __restrict__ w0, const float* __restrict__ w1,
    float* __restrict__ U)
{
    int idx = blockIdx.x * 256 + threadIdx.x;  // = c*16 + r
    if (idx >= 256 * 16) return;
    int c = idx >> 4, r = idx & 15;

    float gr[4][2][2], gi[4][2][2];
    const float inv_sq2 = 0.70710678118654752f;
#pragma unroll
    for (int w = 0; w < 4; ++w) {
        float ty = w0[c * 2 + (w & 1)];
        float tz = w1[c * 2 + (w & 1)];
        float cy = cosf(0.5f * ty), sy = sinf(0.5f * ty);
        float cz = cosf(0.5f * tz), sz = sinf(0.5f * tz);
        // ry @ H2
        float r00 = (cy - sy) * inv_sq2, r01 = (cy + sy) * inv_sq2;
        float r10 = (cy + sy) * inv_sq2, r11 = (sy - cy) * inv_sq2;
        // rz row0 *= ph = cz - i*sz ; row1 *= conj(ph) = cz + i*sz
        gr[w][0][0] = cz * r00; gi[w][0][0] = -sz * r00;
        gr[w][0][1] = cz * r01; gi[w][0][1] = -sz * r01;
        gr[w][1][0] = cz * r10; gi[w][1][0] =  sz * r10;
        gr[w][1][1] = cz * r11; gi[w][1][1] =  sz * r11;
    }
    const int PTOT[16] = {0,13,3,14,6,11,5,8,12,1,15,2,10,7,9,4};
    int rp = PTOT[r];
    float* Uo = U + (size_t)c * 512 + r * 32;
#pragma unroll
    for (int cc = 0; cc < 16; ++cc) {
        float pr = 1.f, pi = 0.f;
#pragma unroll
        for (int w = 0; w < 4; ++w) {
            int ib = (rp >> (3 - w)) & 1, jb = (cc >> (3 - w)) & 1;
            float ar = gr[w][ib][jb], ai = gi[w][ib][jb];
            float nr = pr * ar - pi * ai;
            float ni = pr * ai + pi * ar;
            pr = nr; pi = ni;
        }
        Uo[cc * 2 + 0] = pr;
        Uo[cc * 2 + 1] = pi;
    }
}

// ---------------------------------------------------------------------------
// conv1: 1 -> 32 channels, 256x256, 3x3 pad 1, + BN + ReLU.
// Block: 16x16 spatial tile, 1 thread/pixel, loops 32 out channels.
// ---------------------------------------------------------------------------
__global__ __launch_bounds__(256) void conv1_bn_relu(
    const float* __restrict__ x,   // (8,1,256,256)
    const float* __restrict__ wt,  // (32,1,3,3)
    const float* __restrict__ g, const float* __restrict__ be,
    float* __restrict__ out)       // (8,32,256,256)
{
    __shared__ float s_in[18][18];
    __shared__ float s_w[288];
    int bid = blockIdx.x;
    int tile = bid & 255;          // 16x16 tiles over 256x256
    int b = bid >> 8;
    int tx0 = (tile & 15) * 16, ty0 = (tile >> 4) * 16;
    int tid = threadIdx.x;

    for (int i = tid; i < 288; i += 256) s_w[i] = wt[i];
    for (int i = tid; i < 18 * 18; i += 256) {
        int yy = i / 18, xx = i % 18;
        int gy = ty0 + yy - 1, gx = tx0 + xx - 1;
        float v = 0.f;
        if (gy >= 0 && gy < 256 && gx >= 0 && gx < 256)
            v = x[(size_t)b * 65536 + gy * 256 + gx];
        s_in[yy][xx] = v;
    }
    __syncthreads();

    int px = tid & 15, py = tid >> 4;
    float t[3][3];
#pragma unroll
    for (int i = 0; i < 3; ++i)
#pragma unroll
        for (int j = 0; j < 3; ++j) t[i][j] = s_in[py + i][px + j];

    size_t obase = ((size_t)b * 32) * 65536 + (size_t)(ty0 + py) * 256 + (tx0 + px);
#pragma unroll 4
    for (int oc = 0; oc < 32; ++oc) {
        const float* wr = &s_w[oc * 9];
        float s = wr[0]*t[0][0] + wr[1]*t[0][1] + wr[2]*t[0][2]
                + wr[3]*t[1][0] + wr[4]*t[1][1] + wr[5]*t[1][2]
                + wr[6]*t[2][0] + wr[7]*t[2][1] + wr[8]*t[2][2];
        s = s * (g[oc] * BN_INV) + be[oc];
        out[obase + (size_t)oc * 65536] = fmaxf(s, 0.f);
    }
}

// ---------------------------------------------------------------------------
// 2x2 maxpool, stride 2
// ---------------------------------------------------------------------------
template <int CH, int HW>
__global__ __launch_bounds__(256) void maxpool2_kernel(
    const float* __restrict__ in, float* __restrict__ out)
{
    constexpr int OW = HW / 2;
    int i = blockIdx.x * 256 + threadIdx.x;
    int n = 8 * CH * OW * OW;
    if (i >= n) return;
    int x = i % OW;
    int rest = i / OW;
    int y = rest % OW;
    int bc = rest / OW;
    const float2* r0 = (const float2*)(in + ((size_t)bc * HW + 2 * y) * HW);
    const float2* r1 = (const float2*)(in + ((size_t)bc * HW + 2 * y + 1) * HW);
    float2 a = r0[x], b = r1[x];
    out[i] = fmaxf(fmaxf(a.x, a.y), fmaxf(b.x, b.y));
}

// ---------------------------------------------------------------------------
// Generic 3x3 conv + BN + ReLU, pad 1.
// Block tile: 16 out-channels x 16x16 spatial. 256 threads, each 4 oc x 2x2 px.
// In-channels staged in LDS in chunks of 8.
// ---------------------------------------------------------------------------
template <int CIN, int COUT, int HW>
__global__ __launch_bounds__(256) void conv3x3_bn_relu(
    const float* __restrict__ in,   // (8,CIN,HW,HW)
    const float* __restrict__ wt,   // (COUT,CIN,3,3)
    const float* __restrict__ g, const float* __restrict__ be,
    float* __restrict__ out)        // (8,COUT,HW,HW)
{
    constexpr int ICB = 8;
    constexpr int TS = 16;
    constexpr int OCB = 16;
    constexpr int XT = TS + 2;  // 18
    __shared__ float s_in[ICB][XT][XT];
    __shared__ float s_w[OCB * ICB * 9];

    constexpr int NTX = HW / TS;
    int bid = blockIdx.x;
    int tileid = bid % (NTX * NTX);
    int rest = bid / (NTX * NTX);
    int ocg = rest % (COUT / OCB);
    int b = rest / (COUT / OCB);
    int tx0 = (tileid % NTX) * TS;
    int ty0 = (tileid / NTX) * TS;
    int oc0 = ocg * OCB;

    int tid = threadIdx.x;
    int ocq = tid >> 6;       // 0..3 -> oc = oc0 + ocq*4 + o
    int pos = tid & 63;
    int px = (pos & 7) * 2;
    int py = (pos >> 3) * 2;

    float acc[4][2][2] = {};

    const float* inb = in + (size_t)b * CIN * HW * HW;
    for (int ic0 = 0; ic0 < CIN; ic0 += ICB) {
        for (int idx = tid; idx < ICB * XT * XT; idx += 256) {
            int ic = idx / (XT * XT);
            int r = idx % (XT * XT);
            int yy = r / XT, xx = r % XT;
            int gy = ty0 + yy - 1, gx = tx0 + xx - 1;
            float v = 0.f;
            if (gy >= 0 && gy < HW && gx >= 0 && gx < HW)
                v = inb[(size_t)(ic0 + ic) * HW * HW + gy * HW + gx];
            s_in[ic][yy][xx] = v;
        }
        for (int idx = tid; idx < OCB * ICB * 9; idx += 256) {
            int o = idx / (ICB * 9);
            int r = idx % (ICB * 9);
            s_w[o * (ICB * 9) + r] = wt[(size_t)(oc0 + o) * CIN * 9 + ic0 * 9 + r];
        }
        __syncthreads();

#pragma unroll
        for (int ic = 0; ic < ICB; ++ic) {
            float t[4][4];
#pragma unroll
            for (int i = 0; i < 4; ++i)
#pragma unroll
                for (int j = 0; j < 4; ++j)
                    t[i][j] = s_in[ic][py + i][px + j];
#pragma unroll
            for (int o = 0; o < 4; ++o) {
                const float* wr = &s_w[((ocq * 4 + o) * ICB + ic) * 9];
                float w0 = wr[0], w1 = wr[1], w2 = wr[2];
                float w3 = wr[3], w4 = wr[4], w5 = wr[5];
                float w6 = wr[6], w7 = wr[7], w8 = wr[8];
#pragma unroll
                for (int dy = 0; dy < 2; ++dy)
#pragma unroll
                    for (int dx = 0; dx < 2; ++dx) {
                        acc[o][dy][dx] += w0 * t[dy + 0][dx + 0] + w1 * t[dy + 0][dx + 1] + w2 * t[dy + 0][dx + 2]
                                        + w3 * t[dy + 1][dx + 0] + w4 * t[dy + 1][dx + 1] + w5 * t[dy + 1][dx + 2]
                                        + w6 * t[dy + 2][dx + 0] + w7 * t[dy + 2][dx + 1] + w8 * t[dy + 2][dx + 2];
                    }
            }
        }
        __syncthreads();
    }

#pragma unroll
    for (int o = 0; o < 4; ++o) {
        int oc = oc0 + ocq * 4 + o;
        float sc = g[oc] * BN_INV, bi = be[oc];
#pragma unroll
        for (int dy = 0; dy < 2; ++dy) {
            size_t row = ((size_t)(b * COUT + oc) * HW + (ty0 + py + dy)) * HW + (tx0 + px);
#pragma unroll
            for (int dx = 0; dx < 2; ++dx) {
                float v = acc[o][dy][dx] * sc + bi;
                out[row + dx] = fmaxf(v, 0.f);
            }
        }
    }
}

// ---------------------------------------------------------------------------
// Quantum stage + BN + ReLU.
// One block per (b,c) 32x32 plane; plane + U[c] staged in LDS.
// Each thread handles 4 sites; 16x16 complex matvec on normalized 4x4 patch.
// ev.mean over wires folds to zmean[i] = 1 - popcount(i)/2.
// ---------------------------------------------------------------------------
__global__ __launch_bounds__(256) void quantum_bn_relu(
    const float* __restrict__ e4,  // (8,256,32,32)
    const float* __restrict__ U,   // (256,16,16,2)
    const float* __restrict__ g5, const float* __restrict__ b5,
    float* __restrict__ out)       // (8,256,32,32)
{
    int blk = blockIdx.x;      // b*256 + c
    int c = blk & 255;
    __shared__ float sp[32][32];
    __shared__ float sU[512];

    int tid = threadIdx.x;
    const float* plane = e4 + (size_t)blk * 1024;
#pragma unroll
    for (int k = 0; k < 4; ++k)
        ((float*)sp)[tid + 256 * k] = plane[tid + 256 * k];
    for (int i = tid; i < 512; i += 256) sU[i] = U[(size_t)c * 512 + i];
    __syncthreads();

    // gather taps for 4 sites
    float t[4][16];
    float inv2[4];
#pragma unroll
    for (int k = 0; k < 4; ++k) {
        int site = tid + 256 * k;
        int y = site >> 5, x = site & 31;
        float ss = 0.f;
#pragma unroll
        for (int i = 0; i < 4; ++i)
#pragma unroll
            for (int j = 0; j < 4; ++j) {
                int yy = y + i - 1, xx = x + j - 1;
                float v = (yy >= 0 && yy < 32 && xx >= 0 && xx < 32) ? sp[yy][xx] : 0.f;
                t[k][i * 4 + j] = v;
                ss += v * v;
            }
        float inv = 1.f / fmaxf(sqrtf(ss), 1e-12f);
        inv2[k] = inv * inv;
    }

    float s[4] = {0.f, 0.f, 0.f, 0.f};
#pragma unroll
    for (int i = 0; i < 16; ++i) {
        float re[4] = {0.f, 0.f, 0.f, 0.f};
        float im[4] = {0.f, 0.f, 0.f, 0.f};
#pragma unroll
        for (int j = 0; j < 16; ++j) {
            float ur = sU[(i * 16 + j) * 2 + 0];
            float ui = sU[(i * 16 + j) * 2 + 1];
#pragma unroll
            for (int k = 0; k < 4; ++k) {
                re[k] += ur * t[k][j];
                im[k] += ui * t[k][j];
            }
        }
        float zm = 1.f - 0.5f * (float)__popc(i);
#pragma unroll
        for (int k = 0; k < 4; ++k)
            s[k] += (re[k] * re[k] + im[k] * im[k]) * zm;
    }

    float sc = g5[c] * BN_INV, bi = b5[c];
#pragma unroll
    for (int k = 0; k < 4; ++k) {
        float q = (s[k] * inv2[k] + 1.f) * 0.5f;
        float o = fmaxf(q * sc + bi, 0.f);
        out[(size_t)blk * 1024 + tid + 256 * k] = o;
    }
}

// ---------------------------------------------------------------------------
extern "C" void kernel_launch(void* const* d_in, const int* in_sizes, int n_in,
                              void* d_out, int out_size, void* d_ws, size_t ws_size,
                              hipStream_t stream)
{
    const float* x   = (const float*)d_in[0];
    const float* w1  = (const float*)d_in[1];
    const float* g1  = (const float*)d_in[2];
    const float* b1  = (const float*)d_in[3];
    const float* w2  = (const float*)d_in[4];
    const float* g2  = (const float*)d_in[5];
    const float* b2  = (const float*)d_in[6];
    const float* w3  = (const float*)d_in[7];
    const float* g3  = (const float*)d_in[8];
    const float* b3  = (const float*)d_in[9];
    const float* w4  = (const float*)d_in[10];
    const float* g4  = (const float*)d_in[11];
    const float* b4  = (const float*)d_in[12];
    const float* qw0 = (const float*)d_in[13];
    const float* qw1 = (const float*)d_in[14];
    const float* g5  = (const float*)d_in[15];
    const float* b5  = (const float*)d_in[16];

    float* out = (float*)d_out;
    float* e1  = out;                         // 8*32*256*256 = 16777216
    float* e2  = out + 16777216;              // 8*64*128*128 =  8388608
    float* e3  = out + 25165824;              // 8*128*64*64  =  4194304
    float* o4  = out + 29360128;              // 8*256*32*32  =  2097152

    float* ws = (float*)d_ws;
    // lifetimes: p1 dead after conv2; p2 dead after conv3; p3 dead after conv4
    float* p1 = ws;                 // 4194304 floats @ [0, 4194304)
    float* p2 = ws;                 // 2097152 floats @ [0, 2097152)
    float* p3 = ws;                 // 1048576 floats @ [0, 1048576)
    float* e4 = ws + 1048576;       // 2097152 floats @ [1048576, 3145728)
    float* Uw = ws + 4194304;       //  131072 floats @ [4194304, 4325376)

    build_U_kernel<<<16, 256, 0, stream>>>(qw0, qw1, Uw);

    conv1_bn_relu<<<8 * 256, 256, 0, stream>>>(x, w1, g1, b1, e1);
    maxpool2_kernel<32, 256><<<(4194304 + 255) / 256, 256, 0, stream>>>(e1, p1);

    conv3x3_bn_relu<32, 64, 128><<<64 * 4 * 8, 256, 0, stream>>>(p1, w2, g2, b2, e2);
    maxpool2_kernel<64, 128><<<(2097152 + 255) / 256, 256, 0, stream>>>(e2, p2);

    conv3x3_bn_relu<64, 128, 64><<<16 * 8 * 8, 256, 0, stream>>>(p2, w3, g3, b3, e3);
    maxpool2_kernel<128, 64><<<(1048576 + 255) / 256, 256, 0, stream>>>(e3, p3);

    conv3x3_bn_relu<128, 256, 32><<<4 * 16 * 8, 256, 0, stream>>>(p3, w4, g4, b4, e4);

    quantum_bn_relu<<<2048, 256, 0, stream>>>(e4, Uw, g5, b5, o4);
}

// Round 4
// 336.856 us; speedup vs baseline: 2.9434x; 2.9434x over previous
//
#include <hip/hip_runtime.h>
#include <cstdint>
#include <cstddef>

#define BN_INV 0.9999950000374997f  /* 1/sqrt(1+1e-5) */

typedef __attribute__((ext_vector_type(4))) _Float16 h4v;
typedef __attribute__((ext_vector_type(8))) _Float16 h8v;
typedef __attribute__((ext_vector_type(4))) float f4v;

// split v = hi + lo, both fp16; residual <= 2^-22 * |v|
__device__ __forceinline__ void fsplit(float v, ushort& h, ushort& l) {
    _Float16 hh = (_Float16)v;
    _Float16 ll = (_Float16)(v - (float)hh);
    h = __builtin_bit_cast(ushort, hh);
    l = __builtin_bit_cast(ushort, ll);
}

// ---------------------------------------------------------------------------
// Build per-channel 16x16 complex unitaries U[c] (interleaved re,im).
// ---------------------------------------------------------------------------
__global__ __launch_bounds__(256) void build_U_kernel(
    const float* __restrict__ w0, const float* __restrict__ w1,
    float* __restrict__ U)
{
    int idx = blockIdx.x * 256 + threadIdx.x;  // = c*16 + r
    if (idx >= 256 * 16) return;
    int c = idx >> 4, r = idx & 15;

    float gr[4][2][2], gi[4][2][2];
    const float inv_sq2 = 0.70710678118654752f;
#pragma unroll
    for (int w = 0; w < 4; ++w) {
        float ty = w0[c * 2 + (w & 1)];
        float tz = w1[c * 2 + (w & 1)];
        float cy = cosf(0.5f * ty), sy = sinf(0.5f * ty);
        float cz = cosf(0.5f * tz), sz = sinf(0.5f * tz);
        float r00 = (cy - sy) * inv_sq2, r01 = (cy + sy) * inv_sq2;
        float r10 = (cy + sy) * inv_sq2, r11 = (sy - cy) * inv_sq2;
        gr[w][0][0] = cz * r00; gi[w][0][0] = -sz * r00;
        gr[w][0][1] = cz * r01; gi[w][0][1] = -sz * r01;
        gr[w][1][0] = cz * r10; gi[w][1][0] =  sz * r10;
        gr[w][1][1] = cz * r11; gi[w][1][1] =  sz * r11;
    }
    const int PTOT[16] = {0,13,3,14,6,11,5,8,12,1,15,2,10,7,9,4};
    int rp = PTOT[r];
    float* Uo = U + (size_t)c * 512 + r * 32;
#pragma unroll
    for (int cc = 0; cc < 16; ++cc) {
        float pr = 1.f, pi = 0.f;
#pragma unroll
        for (int w = 0; w < 4; ++w) {
            int ib = (rp >> (3 - w)) & 1, jb = (cc >> (3 - w)) & 1;
            float ar = gr[w][ib][jb], ai = gi[w][ib][jb];
            float nr = pr * ar - pi * ai;
            float ni = pr * ai + pi * ar;
            pr = nr; pi = ni;
        }
        Uo[cc * 2 + 0] = pr;
        Uo[cc * 2 + 1] = pi;
    }
}

// ---------------------------------------------------------------------------
// Repack conv weights (O,I,3,3) fp32 -> split fp16 hi/lo planes, A-frag order:
// dst[(ocg*NCH+chunk)*2 + comp][tap][q][oc64][8j], ic = chunk*32 + q*8 + j
// ---------------------------------------------------------------------------
__global__ __launch_bounds__(256) void repack_w_split(
    const float* __restrict__ w, ushort* __restrict__ dst, int CIN, int COUT)
{
    int i = blockIdx.x * 256 + threadIdx.x;
    if (i >= COUT * CIN * 9) return;
    int ocf = i / (CIN * 9);
    int r = i % (CIN * 9);
    int ic = r / 9;
    int tap = r % 9;
    int ocg = ocf >> 6, oc = ocf & 63;
    int chunk = ic >> 5, q = (ic >> 3) & 3, j = ic & 7;
    int nch = CIN >> 5;
    ushort h, l;
    fsplit(w[i], h, l);
    size_t base = (size_t)((ocg * nch + chunk) * 2) * 18432
                + (size_t)tap * 2048 + q * 512 + oc * 8 + j;
    dst[base] = h;
    dst[base + 18432] = l;
}

// ---------------------------------------------------------------------------
// conv1: 1 -> 32 channels, 256x256, 3x3 pad 1, + BN + ReLU (fp32).
// ---------------------------------------------------------------------------
__global__ __launch_bounds__(256) void conv1_bn_relu(
    const float* __restrict__ x,   // (8,1,256,256)
    const float* __restrict__ wt,  // (32,1,3,3)
    const float* __restrict__ g, const float* __restrict__ be,
    float* __restrict__ out)       // (8,32,256,256)
{
    __shared__ float s_in[18][18];
    __shared__ float s_w[288];
    int bid = blockIdx.x;
    int tile = bid & 255;
    int b = bid >> 8;
    int tx0 = (tile & 15) * 16, ty0 = (tile >> 4) * 16;
    int tid = threadIdx.x;

    for (int i = tid; i < 288; i += 256) s_w[i] = wt[i];
    for (int i = tid; i < 18 * 18; i += 256) {
        int yy = i / 18, xx = i % 18;
        int gy = ty0 + yy - 1, gx = tx0 + xx - 1;
        float v = 0.f;
        if (gy >= 0 && gy < 256 && gx >= 0 && gx < 256)
            v = x[(size_t)b * 65536 + gy * 256 + gx];
        s_in[yy][xx] = v;
    }
    __syncthreads();

    int px = tid & 15, py = tid >> 4;
    float t[3][3];
#pragma unroll
    for (int i = 0; i < 3; ++i)
#pragma unroll
        for (int j = 0; j < 3; ++j) t[i][j] = s_in[py + i][px + j];

    size_t obase = ((size_t)b * 32) * 65536 + (size_t)(ty0 + py) * 256 + (tx0 + px);
#pragma unroll 4
    for (int oc = 0; oc < 32; ++oc) {
        const float* wr = &s_w[oc * 9];
        float s = wr[0]*t[0][0] + wr[1]*t[0][1] + wr[2]*t[0][2]
                + wr[3]*t[1][0] + wr[4]*t[1][1] + wr[5]*t[1][2]
                + wr[6]*t[2][0] + wr[7]*t[2][1] + wr[8]*t[2][2];
        s = s * (g[oc] * BN_INV) + be[oc];
        out[obase + (size_t)oc * 65536] = fmaxf(s, 0.f);
    }
}

// ---------------------------------------------------------------------------
// 2x2 maxpool fp32 NCHW -> split fp16 channel-last: site layout [hi C][lo C]
// ---------------------------------------------------------------------------
template <int C, int HWI>
__global__ __launch_bounds__(256) void pool_split(
    const float* __restrict__ in, ushort* __restrict__ outp)
{
    constexpr int OW = HWI / 2;
    int i = blockIdx.x * 256 + threadIdx.x;
    if (i >= 8 * OW * OW) return;
    int x = i % OW;
    int rest = i / OW;
    int y = rest % OW;
    int b = rest / OW;

    const float* base0 = in + ((size_t)(b * C) * HWI + 2 * y) * HWI + 2 * x;
    ushort* op = outp + ((size_t)(b * OW + y) * OW + x) * (2 * C);
#pragma unroll
    for (int k = 0; k < C / 8; ++k) {
        ushort bh[8], bl[8];
#pragma unroll
        for (int cc = 0; cc < 8; ++cc) {
            int c = k * 8 + cc;
            const float2 r0 = *(const float2*)(base0 + (size_t)c * HWI * HWI);
            const float2 r1 = *(const float2*)(base0 + (size_t)c * HWI * HWI + HWI);
            float m = fmaxf(fmaxf(r0.x, r0.y), fmaxf(r1.x, r1.y));
            fsplit(m, bh[cc], bl[cc]);
        }
        uint4 uh, ul;
        uh.x = (uint)bh[0] | ((uint)bh[1] << 16);
        uh.y = (uint)bh[2] | ((uint)bh[3] << 16);
        uh.z = (uint)bh[4] | ((uint)bh[5] << 16);
        uh.w = (uint)bh[6] | ((uint)bh[7] << 16);
        ul.x = (uint)bl[0] | ((uint)bl[1] << 16);
        ul.y = (uint)bl[2] | ((uint)bl[3] << 16);
        ul.z = (uint)bl[4] | ((uint)bl[5] << 16);
        ul.w = (uint)bl[6] | ((uint)bl[7] << 16);
        *(uint4*)(op + 8 * k) = uh;
        *(uint4*)(op + C + 8 * k) = ul;
    }
}

// ---------------------------------------------------------------------------
// Split-fp16 MFMA implicit-GEMM 3x3 conv + BN + ReLU (near-fp32 accuracy).
// Input: (8,HW,HW,2*CIN) = per-site [hi CIN][lo CIN]. Weights: split-packed.
// acc += Wh*Bh + Wh*Bl + Wl*Bh  (3 MFMAs per product; error ~2^-22).
// Block: 4 waves, 64 oc x 64 sites (8x8). Two weight passes per ic-chunk
// (Wh then Wl restaged into the same 36.9KB LDS plane) keeps LDS at 50.4KB.
// Input LDS pos-stride = 68 ushorts -> B-reads hit 4 lanes/bank (saturating).
// ---------------------------------------------------------------------------
template <int CIN, int COUT, int HW>
__global__ __launch_bounds__(256) void conv3x3_mfma_split(
    const ushort* __restrict__ in,   // (8,HW,HW,2*CIN) split fp16
    const ushort* __restrict__ wb,   // packed split
    const float* __restrict__ g, const float* __restrict__ be,
    float* __restrict__ out)         // (8,COUT,HW,HW) fp32
{
    constexpr int NCH = CIN / 32;
    constexpr int NTX = HW / 8;
    constexpr int NT = NTX * NTX;
    constexpr int NOCG = COUT / 64;
    constexpr int PS = 68;

    __shared__ __align__(16) ushort s_in[100 * PS];       // 13600 B
    __shared__ __align__(16) ushort s_w[9 * 4 * 64 * 8];  // 36864 B

    int bid = blockIdx.x;
    int tile = bid % NT;
    int rest = bid / NT;
    int ocg = rest % NOCG;
    int b = rest / NOCG;
    int x0 = (tile % NTX) * 8;
    int y0 = (tile / NTX) * 8;

    int tid = threadIdx.x;
    int wv = tid >> 6;
    int lane = tid & 63;
    int n = lane & 15;
    int q = lane >> 4;
    int oc_half = (wv & 1) * 32;
    int site_half = (wv >> 1) * 32;

    int s0 = site_half + n;
    int s1 = site_half + 16 + n;
    int ib0 = ((s0 >> 3) * 10 + (s0 & 7)) * PS + q * 8;
    int ib1 = ((s1 >> 3) * 10 + (s1 & 7)) * PS + q * 8;
    int iw0 = q * 512 + (oc_half + n) * 8;
    int iw1 = q * 512 + (oc_half + 16 + n) * 8;

    const ushort* inb = in + (size_t)b * HW * HW * 2 * CIN;

    f4v acc[2][2];
#pragma unroll
    for (int a = 0; a < 2; ++a)
#pragma unroll
        for (int c = 0; c < 2; ++c) acc[a][c] = (f4v){0.f, 0.f, 0.f, 0.f};

    for (int ch = 0; ch < NCH; ++ch) {
        if (ch) __syncthreads();
        // stage input halo: 100 pos x {hi,lo} x 8 uint2-units (4 ic each)
#pragma unroll
        for (int it = 0; it < 7; ++it) {
            int i = tid + it * 256;
            if (i < 1600) {
                int pos = i >> 4;
                int r2 = i & 15;
                int comp = r2 >> 3;
                int u = r2 & 7;
                int py = pos / 10, px = pos % 10;
                int gy = y0 - 1 + py, gx = x0 - 1 + px;
                uint2 v; v.x = 0u; v.y = 0u;
                if (gy >= 0 && gy < HW && gx >= 0 && gx < HW)
                    v = *(const uint2*)(inb + ((size_t)gy * HW + gx) * (2 * CIN)
                                        + comp * CIN + ch * 32 + u * 4);
                *(uint2*)(&s_in[pos * PS + comp * 32 + u * 4]) = v;
            }
        }
        // stage W_hi plane: 2304 uint4
        const uint4* wsrc = (const uint4*)(wb + (size_t)((ocg * NCH + ch) * 2) * 18432);
#pragma unroll
        for (int it = 0; it < 9; ++it) {
            int i = tid + it * 256;
            *(uint4*)(&s_w[i * 8]) = wsrc[i];
        }
        __syncthreads();

        // pass 1: Wh*Bh + Wh*Bl
#pragma unroll
        for (int tap = 0; tap < 9; ++tap) {
            const int toff = ((tap / 3) * 10 + (tap % 3)) * PS;
            const int woff = tap * 2048;
            h8v a0 = *(const h8v*)(&s_w[woff + iw0]);
            h8v a1 = *(const h8v*)(&s_w[woff + iw1]);
            h4v p0 = *(const h4v*)(&s_in[toff + ib0]);
            h4v p1 = *(const h4v*)(&s_in[toff + ib0 + 4]);
            h4v p2 = *(const h4v*)(&s_in[toff + ib1]);
            h4v p3 = *(const h4v*)(&s_in[toff + ib1 + 4]);
            h4v l0 = *(const h4v*)(&s_in[toff + ib0 + 32]);
            h4v l1 = *(const h4v*)(&s_in[toff + ib0 + 36]);
            h4v l2 = *(const h4v*)(&s_in[toff + ib1 + 32]);
            h4v l3 = *(const h4v*)(&s_in[toff + ib1 + 36]);
            h8v bh0 = __builtin_shufflevector(p0, p1, 0, 1, 2, 3, 4, 5, 6, 7);
            h8v bh1 = __builtin_shufflevector(p2, p3, 0, 1, 2, 3, 4, 5, 6, 7);
            h8v bl0 = __builtin_shufflevector(l0, l1, 0, 1, 2, 3, 4, 5, 6, 7);
            h8v bl1 = __builtin_shufflevector(l2, l3, 0, 1, 2, 3, 4, 5, 6, 7);
            acc[0][0] = __builtin_amdgcn_mfma_f32_16x16x32_f16(a0, bh0, acc[0][0], 0, 0, 0);
            acc[0][1] = __builtin_amdgcn_mfma_f32_16x16x32_f16(a0, bh1, acc[0][1], 0, 0, 0);
            acc[1][0] = __builtin_amdgcn_mfma_f32_16x16x32_f16(a1, bh0, acc[1][0], 0, 0, 0);
            acc[1][1] = __builtin_amdgcn_mfma_f32_16x16x32_f16(a1, bh1, acc[1][1], 0, 0, 0);
            acc[0][0] = __builtin_amdgcn_mfma_f32_16x16x32_f16(a0, bl0, acc[0][0], 0, 0, 0);
            acc[0][1] = __builtin_amdgcn_mfma_f32_16x16x32_f16(a0, bl1, acc[0][1], 0, 0, 0);
            acc[1][0] = __builtin_amdgcn_mfma_f32_16x16x32_f16(a1, bl0, acc[1][0], 0, 0, 0);
            acc[1][1] = __builtin_amdgcn_mfma_f32_16x16x32_f16(a1, bl1, acc[1][1], 0, 0, 0);
        }
        __syncthreads();
        // stage W_lo plane
#pragma unroll
        for (int it = 0; it < 9; ++it) {
            int i = tid + it * 256;
            *(uint4*)(&s_w[i * 8]) = wsrc[i + 2304];
        }
        __syncthreads();

        // pass 2: Wl*Bh
#pragma unroll
        for (int tap = 0; tap < 9; ++tap) {
            const int toff = ((tap / 3) * 10 + (tap % 3)) * PS;
            const int woff = tap * 2048;
            h8v a0 = *(const h8v*)(&s_w[woff + iw0]);
            h8v a1 = *(const h8v*)(&s_w[woff + iw1]);
            h4v p0 = *(const h4v*)(&s_in[toff + ib0]);
            h4v p1 = *(const h4v*)(&s_in[toff + ib0 + 4]);
            h4v p2 = *(const h4v*)(&s_in[toff + ib1]);
            h4v p3 = *(const h4v*)(&s_in[toff + ib1 + 4]);
            h8v bh0 = __builtin_shufflevector(p0, p1, 0, 1, 2, 3, 4, 5, 6, 7);
            h8v bh1 = __builtin_shufflevector(p2, p3, 0, 1, 2, 3, 4, 5, 6, 7);
            acc[0][0] = __builtin_amdgcn_mfma_f32_16x16x32_f16(a0, bh0, acc[0][0], 0, 0, 0);
            acc[0][1] = __builtin_amdgcn_mfma_f32_16x16x32_f16(a0, bh1, acc[0][1], 0, 0, 0);
            acc[1][0] = __builtin_amdgcn_mfma_f32_16x16x32_f16(a1, bh0, acc[1][0], 0, 0, 0);
            acc[1][1] = __builtin_amdgcn_mfma_f32_16x16x32_f16(a1, bh1, acc[1][1], 0, 0, 0);
        }
    }

    // epilogue: D row = oc (q*4+r), col = site (n)
#pragma unroll
    for (int toc = 0; toc < 2; ++toc) {
#pragma unroll
        for (int r = 0; r < 4; ++r) {
            int oc = ocg * 64 + oc_half + toc * 16 + q * 4 + r;
            float sc = g[oc] * BN_INV, bi = be[oc];
#pragma unroll
            for (int ts = 0; ts < 2; ++ts) {
                int s = site_half + ts * 16 + n;
                int y = y0 + (s >> 3), x = x0 + (s & 7);
                float v = acc[toc][ts][r] * sc + bi;
                out[((size_t)(b * COUT + oc) * HW + y) * HW + x] = fmaxf(v, 0.f);
            }
        }
    }
}

// ---------------------------------------------------------------------------
// Quantum stage + BN + ReLU (fp32). Safe in-place (per-block plane).
// ---------------------------------------------------------------------------
__global__ __launch_bounds__(256) void quantum_bn_relu(
    const float* __restrict__ e4,  // (8,256,32,32)
    const float* __restrict__ U,   // (256,16,16,2)
    const float* __restrict__ g5, const float* __restrict__ b5,
    float* __restrict__ out)       // (8,256,32,32)
{
    int blk = blockIdx.x;      // b*256 + c
    int c = blk & 255;
    __shared__ float sp[32][32];
    __shared__ float sU[512];

    int tid = threadIdx.x;
    const float* plane = e4 + (size_t)blk * 1024;
#pragma unroll
    for (int k = 0; k < 4; ++k)
        ((float*)sp)[tid + 256 * k] = plane[tid + 256 * k];
    for (int i = tid; i < 512; i += 256) sU[i] = U[(size_t)c * 512 + i];
    __syncthreads();

    float t[4][16];
    float inv2[4];
#pragma unroll
    for (int k = 0; k < 4; ++k) {
        int site = tid + 256 * k;
        int y = site >> 5, x = site & 31;
        float ss = 0.f;
#pragma unroll
        for (int i = 0; i < 4; ++i)
#pragma unroll
            for (int j = 0; j < 4; ++j) {
                int yy = y + i - 1, xx = x + j - 1;
                float v = (yy >= 0 && yy < 32 && xx >= 0 && xx < 32) ? sp[yy][xx] : 0.f;
                t[k][i * 4 + j] = v;
                ss += v * v;
            }
        float inv = 1.f / fmaxf(sqrtf(ss), 1e-12f);
        inv2[k] = inv * inv;
    }

    float s[4] = {0.f, 0.f, 0.f, 0.f};
#pragma unroll
    for (int i = 0; i < 16; ++i) {
        float re[4] = {0.f, 0.f, 0.f, 0.f};
        float im[4] = {0.f, 0.f, 0.f, 0.f};
#pragma unroll
        for (int j = 0; j < 16; ++j) {
            float ur = sU[(i * 16 + j) * 2 + 0];
            float ui = sU[(i * 16 + j) * 2 + 1];
#pragma unroll
            for (int k = 0; k < 4; ++k) {
                re[k] += ur * t[k][j];
                im[k] += ui * t[k][j];
            }
        }
        float zm = 1.f - 0.5f * (float)__popc(i);
#pragma unroll
        for (int k = 0; k < 4; ++k)
            s[k] += (re[k] * re[k] + im[k] * im[k]) * zm;
    }

    float sc = g5[c] * BN_INV, bi = b5[c];
#pragma unroll
    for (int k = 0; k < 4; ++k) {
        float q = (s[k] * inv2[k] + 1.f) * 0.5f;
        float o = fmaxf(q * sc + bi, 0.f);
        out[(size_t)blk * 1024 + tid + 256 * k] = o;
    }
}

// ---------------------------------------------------------------------------
extern "C" void kernel_launch(void* const* d_in, const int* in_sizes, int n_in,
                              void* d_out, int out_size, void* d_ws, size_t ws_size,
                              hipStream_t stream)
{
    const float* x   = (const float*)d_in[0];
    const float* w1  = (const float*)d_in[1];
    const float* g1  = (const float*)d_in[2];
    const float* b1  = (const float*)d_in[3];
    const float* w2  = (const float*)d_in[4];
    const float* g2  = (const float*)d_in[5];
    const float* b2  = (const float*)d_in[6];
    const float* w3  = (const float*)d_in[7];
    const float* g3  = (const float*)d_in[8];
    const float* b3  = (const float*)d_in[9];
    const float* w4  = (const float*)d_in[10];
    const float* g4  = (const float*)d_in[11];
    const float* b4  = (const float*)d_in[12];
    const float* qw0 = (const float*)d_in[13];
    const float* qw1 = (const float*)d_in[14];
    const float* g5  = (const float*)d_in[15];
    const float* b5  = (const float*)d_in[16];

    float* out = (float*)d_out;
    float* e1  = out;                         // 8*32*256*256 = 16777216
    float* e2  = out + 16777216;              // 8*64*128*128 =  8388608
    float* e3  = out + 25165824;              // 8*128*64*64  =  4194304
    float* o4  = out + 29360128;              // 8*256*32*32  =  2097152

    float* ws = (float*)d_ws;
    // floats: Uw@0(131072) wb2@131072(18432) wb3@149504(73728)
    // wb4@223232(294912) pt@518144(4194304, p1/p2/p3 aliased). ~18.9 MB.
    // e4 lives in the o4 slot of d_out (quantum is safely in-place).
    float*  Uw  = ws;
    ushort* wb2 = (ushort*)(ws + 131072);
    ushort* wb3 = (ushort*)(ws + 149504);
    ushort* wb4 = (ushort*)(ws + 223232);
    ushort* pt  = (ushort*)(ws + 518144);

    build_U_kernel<<<16, 256, 0, stream>>>(qw0, qw1, Uw);
    repack_w_split<<<(64 * 32 * 9 + 255) / 256, 256, 0, stream>>>(w2, wb2, 32, 64);
    repack_w_split<<<(128 * 64 * 9 + 255) / 256, 256, 0, stream>>>(w3, wb3, 64, 128);
    repack_w_split<<<(256 * 128 * 9 + 255) / 256, 256, 0, stream>>>(w4, wb4, 128, 256);

    conv1_bn_relu<<<8 * 256, 256, 0, stream>>>(x, w1, g1, b1, e1);
    pool_split<32, 256><<<512, 256, 0, stream>>>(e1, pt);

    conv3x3_mfma_split<32, 64, 128><<<2048, 256, 0, stream>>>(pt, wb2, g2, b2, e2);
    pool_split<64, 128><<<128, 256, 0, stream>>>(e2, pt);

    conv3x3_mfma_split<64, 128, 64><<<1024, 256, 0, stream>>>(pt, wb3, g3, b3, e3);
    pool_split<128, 64><<<32, 256, 0, stream>>>(e3, pt);

    conv3x3_mfma_split<128, 256, 32><<<512, 256, 0, stream>>>(pt, wb4, g4, b4, o4);

    quantum_bn_relu<<<2048, 256, 0, stream>>>(o4, Uw, g5, b5, o4);
}

// Round 5
// 321.591 us; speedup vs baseline: 3.0831x; 1.0475x over previous
//
#include <hip/hip_runtime.h>
#include <cstdint>
#include <cstddef>

#define BN_INV 0.9999950000374997f  /* 1/sqrt(1+1e-5) */

typedef __attribute__((ext_vector_type(4))) _Float16 h4v;
typedef __attribute__((ext_vector_type(8))) _Float16 h8v;
typedef __attribute__((ext_vector_type(4))) float f4v;

// split v = hi + lo, both fp16; residual <= 2^-22 * |v|
__device__ __forceinline__ void fsplit(float v, ushort& h, ushort& l) {
    _Float16 hh = (_Float16)v;
    _Float16 ll = (_Float16)(v - (float)hh);
    h = __builtin_bit_cast(ushort, hh);
    l = __builtin_bit_cast(ushort, ll);
}

// ---------------------------------------------------------------------------
// Repack helper: (O,I,3,3) fp32 -> split fp16 hi/lo planes, A-frag order.
// dst[(ocg*NCH+chunk)*2*18432 ...]: [tap][q][oc64][8j], ic = chunk*32+q*8+j
// ---------------------------------------------------------------------------
__device__ __forceinline__ void repack_one(
    const float* __restrict__ w, ushort* __restrict__ dst, int CIN, int i)
{
    int ocf = i / (CIN * 9);
    int r = i % (CIN * 9);
    int ic = r / 9;
    int tap = r % 9;
    int ocg = ocf >> 6, oc = ocf & 63;
    int chunk = ic >> 5, q = (ic >> 3) & 3, j = ic & 7;
    int nch = CIN >> 5;
    ushort h, l;
    fsplit(w[i], h, l);
    size_t base = (size_t)((ocg * nch + chunk) * 2) * 18432
                + (size_t)tap * 2048 + q * 512 + oc * 8 + j;
    dst[base] = h;
    dst[base + 18432] = l;
}

// ---------------------------------------------------------------------------
// Prep: build U (blocks 0..15) + repack w2/w3/w4 (blocks 16..1527).
// ---------------------------------------------------------------------------
__global__ __launch_bounds__(256) void prep_kernel(
    const float* __restrict__ w0, const float* __restrict__ w1,
    float* __restrict__ U,
    const float* __restrict__ w2, ushort* __restrict__ wb2,
    const float* __restrict__ w3, ushort* __restrict__ wb3,
    const float* __restrict__ w4, ushort* __restrict__ wb4)
{
    int blk = blockIdx.x;
    int tid = threadIdx.x;
    if (blk >= 16 + 72 + 288) { repack_one(w4, wb4, 128, (blk - 376) * 256 + tid); return; }
    if (blk >= 16 + 72)       { repack_one(w3, wb3,  64, (blk -  88) * 256 + tid); return; }
    if (blk >= 16)            { repack_one(w2, wb2,  32, (blk -  16) * 256 + tid); return; }

    int idx = blk * 256 + tid;  // = c*16 + r
    int c = idx >> 4, r = idx & 15;

    float gr[4][2][2], gi[4][2][2];
    const float inv_sq2 = 0.70710678118654752f;
#pragma unroll
    for (int w = 0; w < 4; ++w) {
        float ty = w0[c * 2 + (w & 1)];
        float tz = w1[c * 2 + (w & 1)];
        float cy = cosf(0.5f * ty), sy = sinf(0.5f * ty);
        float cz = cosf(0.5f * tz), sz = sinf(0.5f * tz);
        float r00 = (cy - sy) * inv_sq2, r01 = (cy + sy) * inv_sq2;
        float r10 = (cy + sy) * inv_sq2, r11 = (sy - cy) * inv_sq2;
        gr[w][0][0] = cz * r00; gi[w][0][0] = -sz * r00;
        gr[w][0][1] = cz * r01; gi[w][0][1] = -sz * r01;
        gr[w][1][0] = cz * r10; gi[w][1][0] =  sz * r10;
        gr[w][1][1] = cz * r11; gi[w][1][1] =  sz * r11;
    }
    const int PTOT[16] = {0,13,3,14,6,11,5,8,12,1,15,2,10,7,9,4};
    int rp = PTOT[r];
    float* Uo = U + (size_t)c * 512 + r * 32;
#pragma unroll
    for (int cc = 0; cc < 16; ++cc) {
        float pr = 1.f, pi = 0.f;
#pragma unroll
        for (int w = 0; w < 4; ++w) {
            int ib = (rp >> (3 - w)) & 1, jb = (cc >> (3 - w)) & 1;
            float ar = gr[w][ib][jb], ai = gi[w][ib][jb];
            float nr = pr * ar - pi * ai;
            float ni = pr * ai + pi * ar;
            pr = nr; pi = ni;
        }
        Uo[cc * 2 + 0] = pr;
        Uo[cc * 2 + 1] = pi;
    }
}

// ---------------------------------------------------------------------------
// conv1 (1->32, 256x256, pad 1) + BN + ReLU -> e1 fp32, FUSED 2x2 pool ->
// split fp16 channel-last pt1 [b][128][128][hi 32 | lo 32].
// Pool via shfl_xor(1)/shfl_xor(16): thread (py,px) even-even writes.
// ---------------------------------------------------------------------------
__global__ __launch_bounds__(256) void conv1_bn_relu_pool(
    const float* __restrict__ x,   // (8,1,256,256)
    const float* __restrict__ wt,  // (32,1,3,3)
    const float* __restrict__ g, const float* __restrict__ be,
    float* __restrict__ out,       // (8,32,256,256)
    ushort* __restrict__ pooled)   // (8,128,128,64)
{
    __shared__ float s_in[18][18];
    __shared__ float s_w[288];
    int bid = blockIdx.x;
    int tile = bid & 255;
    int b = bid >> 8;
    int tx0 = (tile & 15) * 16, ty0 = (tile >> 4) * 16;
    int tid = threadIdx.x;

    for (int i = tid; i < 288; i += 256) s_w[i] = wt[i];
    for (int i = tid; i < 18 * 18; i += 256) {
        int yy = i / 18, xx = i % 18;
        int gy = ty0 + yy - 1, gx = tx0 + xx - 1;
        float v = 0.f;
        if (gy >= 0 && gy < 256 && gx >= 0 && gx < 256)
            v = x[(size_t)b * 65536 + gy * 256 + gx];
        s_in[yy][xx] = v;
    }
    __syncthreads();

    int px = tid & 15, py = tid >> 4;
    float t[3][3];
#pragma unroll
    for (int i = 0; i < 3; ++i)
#pragma unroll
        for (int j = 0; j < 3; ++j) t[i][j] = s_in[py + i][px + j];

    bool wr_pool = ((px & 1) == 0) && ((py & 1) == 0);
    ushort* op = pooled + (((size_t)b * 128 + ((ty0 + py) >> 1)) * 128 + ((tx0 + px) >> 1)) * 64;

    size_t obase = ((size_t)b * 32) * 65536 + (size_t)(ty0 + py) * 256 + (tx0 + px);
#pragma unroll 4
    for (int oc = 0; oc < 32; ++oc) {
        const float* wr = &s_w[oc * 9];
        float s = wr[0]*t[0][0] + wr[1]*t[0][1] + wr[2]*t[0][2]
                + wr[3]*t[1][0] + wr[4]*t[1][1] + wr[5]*t[1][2]
                + wr[6]*t[2][0] + wr[7]*t[2][1] + wr[8]*t[2][2];
        s = s * (g[oc] * BN_INV) + be[oc];
        s = fmaxf(s, 0.f);
        out[obase + (size_t)oc * 65536] = s;
        float p = fmaxf(s, __shfl_xor(s, 1));
        p = fmaxf(p, __shfl_xor(p, 16));
        if (wr_pool) {
            ushort h, l;
            fsplit(p, h, l);
            op[oc] = h;
            op[32 + oc] = l;
        }
    }
}

// ---------------------------------------------------------------------------
// Split-fp16 MFMA implicit-GEMM 3x3 conv + BN + ReLU, optional fused pool.
// Input: (8,HW,HW,2*CIN) split fp16 [hi CIN | lo CIN] per site.
// acc += Wh*Bh + Wh*Bl + Wl*Bh (3 MFMAs/product, err ~2^-22).
// Block: 4 waves, 64 oc x 64 sites (8x8). Pool: shfl_xor over n^1 (x) and
// n^8 (y) -> lanes with (n&9)==0 write pooled split fp16 [hi COUT | lo COUT].
// ---------------------------------------------------------------------------
template <int CIN, int COUT, int HW, bool POOL>
__global__ __launch_bounds__(256) void conv3x3_mfma_split(
    const ushort* __restrict__ in,   // (8,HW,HW,2*CIN)
    const ushort* __restrict__ wb,   // packed split
    const float* __restrict__ g, const float* __restrict__ be,
    float* __restrict__ out,         // (8,COUT,HW,HW) fp32
    ushort* __restrict__ pooled)     // (8,HW/2,HW/2,2*COUT) if POOL
{
    constexpr int NCH = CIN / 32;
    constexpr int NTX = HW / 8;
    constexpr int NT = NTX * NTX;
    constexpr int NOCG = COUT / 64;
    constexpr int PS = 68;

    __shared__ __align__(16) ushort s_in[100 * PS];       // 13600 B
    __shared__ __align__(16) ushort s_w[9 * 4 * 64 * 8];  // 36864 B

    int bid = blockIdx.x;
    int tile = bid % NT;
    int rest = bid / NT;
    int ocg = rest % NOCG;
    int b = rest / NOCG;
    int x0 = (tile % NTX) * 8;
    int y0 = (tile / NTX) * 8;

    int tid = threadIdx.x;
    int wv = tid >> 6;
    int lane = tid & 63;
    int n = lane & 15;
    int q = lane >> 4;
    int oc_half = (wv & 1) * 32;
    int site_half = (wv >> 1) * 32;

    int s0 = site_half + n;
    int s1 = site_half + 16 + n;
    int ib0 = ((s0 >> 3) * 10 + (s0 & 7)) * PS + q * 8;
    int ib1 = ((s1 >> 3) * 10 + (s1 & 7)) * PS + q * 8;
    int iw0 = q * 512 + (oc_half + n) * 8;
    int iw1 = q * 512 + (oc_half + 16 + n) * 8;

    const ushort* inb = in + (size_t)b * HW * HW * 2 * CIN;

    f4v acc[2][2];
#pragma unroll
    for (int a = 0; a < 2; ++a)
#pragma unroll
        for (int c = 0; c < 2; ++c) acc[a][c] = (f4v){0.f, 0.f, 0.f, 0.f};

    for (int ch = 0; ch < NCH; ++ch) {
        if (ch) __syncthreads();
        // stage input halo: 100 pos x {hi,lo} x 8 uint2-units (4 ic each)
#pragma unroll
        for (int it = 0; it < 7; ++it) {
            int i = tid + it * 256;
            if (i < 1600) {
                int pos = i >> 4;
                int r2 = i & 15;
                int comp = r2 >> 3;
                int u = r2 & 7;
                int py = pos / 10, px = pos % 10;
                int gy = y0 - 1 + py, gx = x0 - 1 + px;
                uint2 v; v.x = 0u; v.y = 0u;
                if (gy >= 0 && gy < HW && gx >= 0 && gx < HW)
                    v = *(const uint2*)(inb + ((size_t)gy * HW + gx) * (2 * CIN)
                                        + comp * CIN + ch * 32 + u * 4);
                *(uint2*)(&s_in[pos * PS + comp * 32 + u * 4]) = v;
            }
        }
        // stage W_hi plane: 2304 uint4
        const uint4* wsrc = (const uint4*)(wb + (size_t)((ocg * NCH + ch) * 2) * 18432);
#pragma unroll
        for (int it = 0; it < 9; ++it) {
            int i = tid + it * 256;
            *(uint4*)(&s_w[i * 8]) = wsrc[i];
        }
        __syncthreads();

        // pass 1: Wh*Bh + Wh*Bl
#pragma unroll
        for (int tap = 0; tap < 9; ++tap) {
            const int toff = ((tap / 3) * 10 + (tap % 3)) * PS;
            const int woff = tap * 2048;
            h8v a0 = *(const h8v*)(&s_w[woff + iw0]);
            h8v a1 = *(const h8v*)(&s_w[woff + iw1]);
            h4v p0 = *(const h4v*)(&s_in[toff + ib0]);
            h4v p1 = *(const h4v*)(&s_in[toff + ib0 + 4]);
            h4v p2 = *(const h4v*)(&s_in[toff + ib1]);
            h4v p3 = *(const h4v*)(&s_in[toff + ib1 + 4]);
            h4v l0 = *(const h4v*)(&s_in[toff + ib0 + 32]);
            h4v l1 = *(const h4v*)(&s_in[toff + ib0 + 36]);
            h4v l2 = *(const h4v*)(&s_in[toff + ib1 + 32]);
            h4v l3 = *(const h4v*)(&s_in[toff + ib1 + 36]);
            h8v bh0 = __builtin_shufflevector(p0, p1, 0, 1, 2, 3, 4, 5, 6, 7);
            h8v bh1 = __builtin_shufflevector(p2, p3, 0, 1, 2, 3, 4, 5, 6, 7);
            h8v bl0 = __builtin_shufflevector(l0, l1, 0, 1, 2, 3, 4, 5, 6, 7);
            h8v bl1 = __builtin_shufflevector(l2, l3, 0, 1, 2, 3, 4, 5, 6, 7);
            acc[0][0] = __builtin_amdgcn_mfma_f32_16x16x32_f16(a0, bh0, acc[0][0], 0, 0, 0);
            acc[0][1] = __builtin_amdgcn_mfma_f32_16x16x32_f16(a0, bh1, acc[0][1], 0, 0, 0);
            acc[1][0] = __builtin_amdgcn_mfma_f32_16x16x32_f16(a1, bh0, acc[1][0], 0, 0, 0);
            acc[1][1] = __builtin_amdgcn_mfma_f32_16x16x32_f16(a1, bh1, acc[1][1], 0, 0, 0);
            acc[0][0] = __builtin_amdgcn_mfma_f32_16x16x32_f16(a0, bl0, acc[0][0], 0, 0, 0);
            acc[0][1] = __builtin_amdgcn_mfma_f32_16x16x32_f16(a0, bl1, acc[0][1], 0, 0, 0);
            acc[1][0] = __builtin_amdgcn_mfma_f32_16x16x32_f16(a1, bl0, acc[1][0], 0, 0, 0);
            acc[1][1] = __builtin_amdgcn_mfma_f32_16x16x32_f16(a1, bl1, acc[1][1], 0, 0, 0);
        }
        __syncthreads();
        // stage W_lo plane
#pragma unroll
        for (int it = 0; it < 9; ++it) {
            int i = tid + it * 256;
            *(uint4*)(&s_w[i * 8]) = wsrc[i + 2304];
        }
        __syncthreads();

        // pass 2: Wl*Bh
#pragma unroll
        for (int tap = 0; tap < 9; ++tap) {
            const int toff = ((tap / 3) * 10 + (tap % 3)) * PS;
            const int woff = tap * 2048;
            h8v a0 = *(const h8v*)(&s_w[woff + iw0]);
            h8v a1 = *(const h8v*)(&s_w[woff + iw1]);
            h4v p0 = *(const h4v*)(&s_in[toff + ib0]);
            h4v p1 = *(const h4v*)(&s_in[toff + ib0 + 4]);
            h4v p2 = *(const h4v*)(&s_in[toff + ib1]);
            h4v p3 = *(const h4v*)(&s_in[toff + ib1 + 4]);
            h8v bh0 = __builtin_shufflevector(p0, p1, 0, 1, 2, 3, 4, 5, 6, 7);
            h8v bh1 = __builtin_shufflevector(p2, p3, 0, 1, 2, 3, 4, 5, 6, 7);
            acc[0][0] = __builtin_amdgcn_mfma_f32_16x16x32_f16(a0, bh0, acc[0][0], 0, 0, 0);
            acc[0][1] = __builtin_amdgcn_mfma_f32_16x16x32_f16(a0, bh1, acc[0][1], 0, 0, 0);
            acc[1][0] = __builtin_amdgcn_mfma_f32_16x16x32_f16(a1, bh0, acc[1][0], 0, 0, 0);
            acc[1][1] = __builtin_amdgcn_mfma_f32_16x16x32_f16(a1, bh1, acc[1][1], 0, 0, 0);
        }
    }

    // epilogue: D row = oc (q*4+r), col = site (n); optional fused 2x2 pool
#pragma unroll
    for (int toc = 0; toc < 2; ++toc) {
#pragma unroll
        for (int r = 0; r < 4; ++r) {
            int oc = ocg * 64 + oc_half + toc * 16 + q * 4 + r;
            float sc = g[oc] * BN_INV, bi = be[oc];
#pragma unroll
            for (int ts = 0; ts < 2; ++ts) {
                int s = site_half + ts * 16 + n;
                int y = y0 + (s >> 3), x = x0 + (s & 7);
                float v = fmaxf(acc[toc][ts][r] * sc + bi, 0.f);
                out[((size_t)(b * COUT + oc) * HW + y) * HW + x] = v;
                if (POOL) {
                    float p = fmaxf(v, __shfl_xor(v, 1));
                    p = fmaxf(p, __shfl_xor(p, 8));
                    if ((n & 9) == 0) {
                        ushort h, l;
                        fsplit(p, h, l);
                        ushort* op = pooled
                            + (((size_t)b * (HW / 2) + (y >> 1)) * (HW / 2) + (x >> 1)) * (2 * COUT);
                        op[oc] = h;
                        op[COUT + oc] = l;
                    }
                }
            }
        }
    }
}

// ---------------------------------------------------------------------------
// Quantum stage + BN + ReLU (fp32). In-place safe (per-block plane).
// Only the 10 rows with nonzero Z-mean are computed (popc==2 -> zm=0).
// U rows read as float4 (2 complex entries per ds_read_b128).
// ---------------------------------------------------------------------------
__global__ __launch_bounds__(256) void quantum_bn_relu(
    const float* __restrict__ e4,  // (8,256,32,32)
    const float* __restrict__ U,   // (256,16,16,2)
    const float* __restrict__ g5, const float* __restrict__ b5,
    float* __restrict__ out)       // (8,256,32,32)
{
    int blk = blockIdx.x;      // b*256 + c
    int c = blk & 255;
    __shared__ float sp[32][32];
    __shared__ __align__(16) float sU[512];

    int tid = threadIdx.x;
    const float4* plane4 = (const float4*)(e4 + (size_t)blk * 1024);
    ((float4*)sp)[tid] = plane4[tid];
    const float4* Usrc = (const float4*)(U + (size_t)c * 512);
    if (tid < 128) ((float4*)sU)[tid] = Usrc[tid];
    __syncthreads();

    float t[4][16];
    float inv2[4];
#pragma unroll
    for (int k = 0; k < 4; ++k) {
        int site = tid + 256 * k;
        int y = site >> 5, x = site & 31;
        float ss = 0.f;
#pragma unroll
        for (int i = 0; i < 4; ++i)
#pragma unroll
            for (int j = 0; j < 4; ++j) {
                int yy = y + i - 1, xx = x + j - 1;
                float v = (yy >= 0 && yy < 32 && xx >= 0 && xx < 32) ? sp[yy][xx] : 0.f;
                t[k][i * 4 + j] = v;
                ss += v * v;
            }
        float inv = 1.f / fmaxf(sqrtf(ss), 1e-12f);
        inv2[k] = inv * inv;
    }

    const int   RI[10] = {0, 1, 2, 4, 7, 8, 11, 13, 14, 15};
    const float ZM[10] = {1.f, .5f, .5f, .5f, -.5f, .5f, -.5f, -.5f, -.5f, -1.f};
    const float4* sU4 = (const float4*)sU;

    float s[4] = {0.f, 0.f, 0.f, 0.f};
#pragma unroll
    for (int ii = 0; ii < 10; ++ii) {
        int i = RI[ii];
        float re[4] = {0.f, 0.f, 0.f, 0.f};
        float im[4] = {0.f, 0.f, 0.f, 0.f};
#pragma unroll
        for (int jj = 0; jj < 8; ++jj) {
            float4 u = sU4[i * 8 + jj];
#pragma unroll
            for (int k = 0; k < 4; ++k) {
                re[k] += u.x * t[k][2 * jj];
                im[k] += u.y * t[k][2 * jj];
                re[k] += u.z * t[k][2 * jj + 1];
                im[k] += u.w * t[k][2 * jj + 1];
            }
        }
        float zm = ZM[ii];
#pragma unroll
        for (int k = 0; k < 4; ++k)
            s[k] += (re[k] * re[k] + im[k] * im[k]) * zm;
    }

    float sc = g5[c] * BN_INV, bi = b5[c];
#pragma unroll
    for (int k = 0; k < 4; ++k) {
        float q = (s[k] * inv2[k] + 1.f) * 0.5f;
        float o = fmaxf(q * sc + bi, 0.f);
        out[(size_t)blk * 1024 + tid + 256 * k] = o;
    }
}

// ---------------------------------------------------------------------------
extern "C" void kernel_launch(void* const* d_in, const int* in_sizes, int n_in,
                              void* d_out, int out_size, void* d_ws, size_t ws_size,
                              hipStream_t stream)
{
    const float* x   = (const float*)d_in[0];
    const float* w1  = (const float*)d_in[1];
    const float* g1  = (const float*)d_in[2];
    const float* b1  = (const float*)d_in[3];
    const float* w2  = (const float*)d_in[4];
    const float* g2  = (const float*)d_in[5];
    const float* b2  = (const float*)d_in[6];
    const float* w3  = (const float*)d_in[7];
    const float* g3  = (const float*)d_in[8];
    const float* b3  = (const float*)d_in[9];
    const float* w4  = (const float*)d_in[10];
    const float* g4  = (const float*)d_in[11];
    const float* b4  = (const float*)d_in[12];
    const float* qw0 = (const float*)d_in[13];
    const float* qw1 = (const float*)d_in[14];
    const float* g5  = (const float*)d_in[15];
    const float* b5  = (const float*)d_in[16];

    float* out = (float*)d_out;
    float* e1  = out;                         // 8*32*256*256 = 16777216
    float* e2  = out + 16777216;              // 8*64*128*128 =  8388608
    float* e3  = out + 25165824;              // 8*128*64*64  =  4194304
    float* o4  = out + 29360128;              // 8*256*32*32  =  2097152

    float* ws = (float*)d_ws;
    // floats: Uw@0(131072) wb2@131072(18432) wb3@149504(73728)
    // wb4@223232(294912) pt1@518144(4194304) pt2@4712448(2097152)
    // pt3 aliases pt1 (dead after conv2). Peak ~27.2 MB.
    float*  Uw  = ws;
    ushort* wb2 = (ushort*)(ws + 131072);
    ushort* wb3 = (ushort*)(ws + 149504);
    ushort* wb4 = (ushort*)(ws + 223232);
    ushort* pt1 = (ushort*)(ws + 518144);     // (8,128,128,64)
    ushort* pt2 = (ushort*)(ws + 4712448);    // (8,64,64,128)
    ushort* pt3 = (ushort*)(ws + 518144);     // (8,32,32,256), aliases pt1

    prep_kernel<<<1528, 256, 0, stream>>>(qw0, qw1, Uw, w2, wb2, w3, wb3, w4, wb4);

    conv1_bn_relu_pool<<<8 * 256, 256, 0, stream>>>(x, w1, g1, b1, e1, pt1);

    conv3x3_mfma_split<32, 64, 128, true><<<2048, 256, 0, stream>>>(pt1, wb2, g2, b2, e2, pt2);

    conv3x3_mfma_split<64, 128, 64, true><<<1024, 256, 0, stream>>>(pt2, wb3, g3, b3, e3, pt3);

    conv3x3_mfma_split<128, 256, 32, false><<<512, 256, 0, stream>>>(pt3, wb4, g4, b4, o4, nullptr);

    quantum_bn_relu<<<2048, 256, 0, stream>>>(o4, Uw, g5, b5, o4);
}

// Round 6
// 311.533 us; speedup vs baseline: 3.1826x; 1.0323x over previous
//
#include <hip/hip_runtime.h>
#include <cstdint>
#include <cstddef>

#define BN_INV 0.9999950000374997f  /* 1/sqrt(1+1e-5) */

typedef __attribute__((ext_vector_type(4))) _Float16 h4v;
typedef __attribute__((ext_vector_type(8))) _Float16 h8v;
typedef __attribute__((ext_vector_type(4))) float f4v;

// split v = hi + lo, both fp16; residual <= 2^-22 * |v|
__device__ __forceinline__ void fsplit(float v, ushort& h, ushort& l) {
    _Float16 hh = (_Float16)v;
    _Float16 ll = (_Float16)(v - (float)hh);
    h = __builtin_bit_cast(ushort, hh);
    l = __builtin_bit_cast(ushort, ll);
}

// ---------------------------------------------------------------------------
// Repack helper: (O,I,3,3) fp32 -> split fp16 hi/lo planes, A-frag order.
// dst[(ocg*NCH+chunk)*2*18432 + comp*18432 + tap*2048 + q*512 + oc*8 + j],
// ic = chunk*32 + q*8 + j
// ---------------------------------------------------------------------------
__device__ __forceinline__ void repack_one(
    const float* __restrict__ w, ushort* __restrict__ dst, int CIN, int i)
{
    int ocf = i / (CIN * 9);
    int r = i % (CIN * 9);
    int ic = r / 9;
    int tap = r % 9;
    int ocg = ocf >> 6, oc = ocf & 63;
    int chunk = ic >> 5, q = (ic >> 3) & 3, j = ic & 7;
    int nch = CIN >> 5;
    ushort h, l;
    fsplit(w[i], h, l);
    size_t base = (size_t)((ocg * nch + chunk) * 2) * 18432
                + (size_t)tap * 2048 + q * 512 + oc * 8 + j;
    dst[base] = h;
    dst[base + 18432] = l;
}

// ---------------------------------------------------------------------------
// Prep: build U (blocks 0..15) + repack w2/w3/w4 (blocks 16..1527).
// ---------------------------------------------------------------------------
__global__ __launch_bounds__(256) void prep_kernel(
    const float* __restrict__ w0, const float* __restrict__ w1,
    float* __restrict__ U,
    const float* __restrict__ w2, ushort* __restrict__ wb2,
    const float* __restrict__ w3, ushort* __restrict__ wb3,
    const float* __restrict__ w4, ushort* __restrict__ wb4)
{
    int blk = blockIdx.x;
    int tid = threadIdx.x;
    if (blk >= 16 + 72 + 288) { repack_one(w4, wb4, 128, (blk - 376) * 256 + tid); return; }
    if (blk >= 16 + 72)       { repack_one(w3, wb3,  64, (blk -  88) * 256 + tid); return; }
    if (blk >= 16)            { repack_one(w2, wb2,  32, (blk -  16) * 256 + tid); return; }

    int idx = blk * 256 + tid;  // = c*16 + r
    int c = idx >> 4, r = idx & 15;

    float gr[4][2][2], gi[4][2][2];
    const float inv_sq2 = 0.70710678118654752f;
#pragma unroll
    for (int w = 0; w < 4; ++w) {
        float ty = w0[c * 2 + (w & 1)];
        float tz = w1[c * 2 + (w & 1)];
        float cy = cosf(0.5f * ty), sy = sinf(0.5f * ty);
        float cz = cosf(0.5f * tz), sz = sinf(0.5f * tz);
        float r00 = (cy - sy) * inv_sq2, r01 = (cy + sy) * inv_sq2;
        float r10 = (cy + sy) * inv_sq2, r11 = (sy - cy) * inv_sq2;
        gr[w][0][0] = cz * r00; gi[w][0][0] = -sz * r00;
        gr[w][0][1] = cz * r01; gi[w][0][1] = -sz * r01;
        gr[w][1][0] = cz * r10; gi[w][1][0] =  sz * r10;
        gr[w][1][1] = cz * r11; gi[w][1][1] =  sz * r11;
    }
    const int PTOT[16] = {0,13,3,14,6,11,5,8,12,1,15,2,10,7,9,4};
    int rp = PTOT[r];
    float* Uo = U + (size_t)c * 512 + r * 32;
#pragma unroll
    for (int cc = 0; cc < 16; ++cc) {
        float pr = 1.f, pi = 0.f;
#pragma unroll
        for (int w = 0; w < 4; ++w) {
            int ib = (rp >> (3 - w)) & 1, jb = (cc >> (3 - w)) & 1;
            float ar = gr[w][ib][jb], ai = gi[w][ib][jb];
            float nr = pr * ar - pi * ai;
            float ni = pr * ai + pi * ar;
            pr = nr; pi = ni;
        }
        Uo[cc * 2 + 0] = pr;
        Uo[cc * 2 + 1] = pi;
    }
}

// ---------------------------------------------------------------------------
// conv1 (1->32, 256x256, pad 1) + BN + ReLU -> e1 fp32, FUSED 2x2 pool ->
// split fp16 channel-last pt1 [b][128][128][hi 32 | lo 32].
// Pool via shfl_xor(1)/shfl_xor(16); packed uint4 pooled stores.
// ---------------------------------------------------------------------------
__global__ __launch_bounds__(256) void conv1_bn_relu_pool(
    const float* __restrict__ x,   // (8,1,256,256)
    const float* __restrict__ wt,  // (32,1,3,3)
    const float* __restrict__ g, const float* __restrict__ be,
    float* __restrict__ out,       // (8,32,256,256)
    ushort* __restrict__ pooled)   // (8,128,128,64)
{
    __shared__ float s_in[18][18];
    __shared__ float s_w[288];
    int bid = blockIdx.x;
    int tile = bid & 255;
    int b = bid >> 8;
    int tx0 = (tile & 15) * 16, ty0 = (tile >> 4) * 16;
    int tid = threadIdx.x;

    for (int i = tid; i < 288; i += 256) s_w[i] = wt[i];
    for (int i = tid; i < 18 * 18; i += 256) {
        int yy = i / 18, xx = i % 18;
        int gy = ty0 + yy - 1, gx = tx0 + xx - 1;
        float v = 0.f;
        if (gy >= 0 && gy < 256 && gx >= 0 && gx < 256)
            v = x[(size_t)b * 65536 + gy * 256 + gx];
        s_in[yy][xx] = v;
    }
    __syncthreads();

    int px = tid & 15, py = tid >> 4;
    float t[3][3];
#pragma unroll
    for (int i = 0; i < 3; ++i)
#pragma unroll
        for (int j = 0; j < 3; ++j) t[i][j] = s_in[py + i][px + j];

    bool wr_pool = ((px & 1) == 0) && ((py & 1) == 0);
    ushort ph[32], pl[32];

    size_t obase = ((size_t)b * 32) * 65536 + (size_t)(ty0 + py) * 256 + (tx0 + px);
#pragma unroll 4
    for (int oc = 0; oc < 32; ++oc) {
        const float* wr = &s_w[oc * 9];
        float s = wr[0]*t[0][0] + wr[1]*t[0][1] + wr[2]*t[0][2]
                + wr[3]*t[1][0] + wr[4]*t[1][1] + wr[5]*t[1][2]
                + wr[6]*t[2][0] + wr[7]*t[2][1] + wr[8]*t[2][2];
        s = s * (g[oc] * BN_INV) + be[oc];
        s = fmaxf(s, 0.f);
        out[obase + (size_t)oc * 65536] = s;
        float p = fmaxf(s, __shfl_xor(s, 1));
        p = fmaxf(p, __shfl_xor(p, 16));
        fsplit(p, ph[oc], pl[oc]);
    }
    if (wr_pool) {
        ushort* op = pooled + (((size_t)b * 128 + ((ty0 + py) >> 1)) * 128 + ((tx0 + px) >> 1)) * 64;
#pragma unroll
        for (int k = 0; k < 4; ++k) {
            uint4 u;
            u.x = (uint)ph[8*k+0] | ((uint)ph[8*k+1] << 16);
            u.y = (uint)ph[8*k+2] | ((uint)ph[8*k+3] << 16);
            u.z = (uint)ph[8*k+4] | ((uint)ph[8*k+5] << 16);
            u.w = (uint)ph[8*k+6] | ((uint)ph[8*k+7] << 16);
            *(uint4*)(op + 8 * k) = u;
            uint4 v;
            v.x = (uint)pl[8*k+0] | ((uint)pl[8*k+1] << 16);
            v.y = (uint)pl[8*k+2] | ((uint)pl[8*k+3] << 16);
            v.z = (uint)pl[8*k+4] | ((uint)pl[8*k+5] << 16);
            v.w = (uint)pl[8*k+6] | ((uint)pl[8*k+7] << 16);
            *(uint4*)(op + 32 + 8 * k) = v;
        }
    }
}

// ---------------------------------------------------------------------------
// Split-fp16 MFMA implicit-GEMM 3x3 conv + BN + ReLU, optional fused pool.
// Weights are NOT staged in LDS: each lane loads its A-fragment directly
// from the packed global layout (L2-hot, identical across blocks of an ocg).
// LDS = input halo only (14.4 KB) -> high co-residency, 2 barriers/chunk.
// acc += Wh*Bh + Wh*Bl + Wl*Bh (3 MFMAs/product, err ~2^-22).
// Input LDS pos-stride = 72 ushorts: 16B-aligned ds_read_b128, <=2-way banks.
// ---------------------------------------------------------------------------
template <int CIN, int COUT, int HW, bool POOL>
__global__ __launch_bounds__(256) void conv3x3_mfma_split(
    const ushort* __restrict__ in,   // (8,HW,HW,2*CIN)
    const ushort* __restrict__ wb,   // packed split
    const float* __restrict__ g, const float* __restrict__ be,
    float* __restrict__ out,         // (8,COUT,HW,HW) fp32
    ushort* __restrict__ pooled)     // (8,HW/2,HW/2,2*COUT) if POOL
{
    constexpr int NCH = CIN / 32;
    constexpr int NTX = HW / 8;
    constexpr int NT = NTX * NTX;
    constexpr int NOCG = COUT / 64;
    constexpr int PS = 72;

    __shared__ __align__(16) ushort s_in[100 * PS];  // 14400 B

    int bid = blockIdx.x;
    int tile = bid % NT;
    int rest = bid / NT;
    int ocg = rest % NOCG;
    int b = rest / NOCG;
    int x0 = (tile % NTX) * 8;
    int y0 = (tile / NTX) * 8;

    int tid = threadIdx.x;
    int wv = tid >> 6;
    int lane = tid & 63;
    int n = lane & 15;
    int q = lane >> 4;
    int oc_half = (wv & 1) * 32;
    int site_half = (wv >> 1) * 32;

    int s0 = site_half + n;
    int s1 = site_half + 16 + n;
    int ib0 = ((s0 >> 3) * 10 + (s0 & 7)) * PS + q * 8;
    int ib1 = ((s1 >> 3) * 10 + (s1 & 7)) * PS + q * 8;
    int iwa0 = q * 512 + (oc_half + n) * 8;       // A-frag offset (ushorts)
    int iwa1 = q * 512 + (oc_half + 16 + n) * 8;

    const ushort* inb = in + (size_t)b * HW * HW * 2 * CIN;

    f4v acc[2][2];
#pragma unroll
    for (int a = 0; a < 2; ++a)
#pragma unroll
        for (int c = 0; c < 2; ++c) acc[a][c] = (f4v){0.f, 0.f, 0.f, 0.f};

    for (int ch = 0; ch < NCH; ++ch) {
        if (ch) __syncthreads();
        // stage input halo: 100 pos x {hi,lo} x 8 uint2-units (4 ic each)
#pragma unroll
        for (int it = 0; it < 7; ++it) {
            int i = tid + it * 256;
            if (i < 1600) {
                int pos = i >> 4;
                int r2 = i & 15;
                int comp = r2 >> 3;
                int u = r2 & 7;
                int py = pos / 10, px = pos % 10;
                int gy = y0 - 1 + py, gx = x0 - 1 + px;
                uint2 v; v.x = 0u; v.y = 0u;
                if (gy >= 0 && gy < HW && gx >= 0 && gx < HW)
                    v = *(const uint2*)(inb + ((size_t)gy * HW + gx) * (2 * CIN)
                                        + comp * CIN + ch * 32 + u * 4);
                *(uint2*)(&s_in[pos * PS + comp * 32 + u * 4]) = v;
            }
        }
        __syncthreads();

        const ushort* wc = wb + (size_t)((ocg * NCH + ch) * 2) * 18432;
#pragma unroll
        for (int tap = 0; tap < 9; ++tap) {
            const int toff = ((tap / 3) * 10 + (tap % 3)) * PS;
            const ushort* wt_ = wc + tap * 2048;
            h8v ah0 = *(const h8v*)(wt_ + iwa0);
            h8v ah1 = *(const h8v*)(wt_ + iwa1);
            h8v al0 = *(const h8v*)(wt_ + 18432 + iwa0);
            h8v al1 = *(const h8v*)(wt_ + 18432 + iwa1);
            h8v bh0 = *(const h8v*)(&s_in[toff + ib0]);
            h8v bh1 = *(const h8v*)(&s_in[toff + ib1]);
            h8v bl0 = *(const h8v*)(&s_in[toff + ib0 + 32]);
            h8v bl1 = *(const h8v*)(&s_in[toff + ib1 + 32]);
            acc[0][0] = __builtin_amdgcn_mfma_f32_16x16x32_f16(ah0, bh0, acc[0][0], 0, 0, 0);
            acc[0][1] = __builtin_amdgcn_mfma_f32_16x16x32_f16(ah0, bh1, acc[0][1], 0, 0, 0);
            acc[1][0] = __builtin_amdgcn_mfma_f32_16x16x32_f16(ah1, bh0, acc[1][0], 0, 0, 0);
            acc[1][1] = __builtin_amdgcn_mfma_f32_16x16x32_f16(ah1, bh1, acc[1][1], 0, 0, 0);
            acc[0][0] = __builtin_amdgcn_mfma_f32_16x16x32_f16(ah0, bl0, acc[0][0], 0, 0, 0);
            acc[0][1] = __builtin_amdgcn_mfma_f32_16x16x32_f16(ah0, bl1, acc[0][1], 0, 0, 0);
            acc[1][0] = __builtin_amdgcn_mfma_f32_16x16x32_f16(ah1, bl0, acc[1][0], 0, 0, 0);
            acc[1][1] = __builtin_amdgcn_mfma_f32_16x16x32_f16(ah1, bl1, acc[1][1], 0, 0, 0);
            acc[0][0] = __builtin_amdgcn_mfma_f32_16x16x32_f16(al0, bh0, acc[0][0], 0, 0, 0);
            acc[0][1] = __builtin_amdgcn_mfma_f32_16x16x32_f16(al0, bh1, acc[0][1], 0, 0, 0);
            acc[1][0] = __builtin_amdgcn_mfma_f32_16x16x32_f16(al1, bh0, acc[1][0], 0, 0, 0);
            acc[1][1] = __builtin_amdgcn_mfma_f32_16x16x32_f16(al1, bh1, acc[1][1], 0, 0, 0);
        }
    }

    // epilogue: D row = oc (q*4+r), col = site (n); optional fused 2x2 pool
#pragma unroll
    for (int toc = 0; toc < 2; ++toc) {
#pragma unroll
        for (int ts = 0; ts < 2; ++ts) {
            int s = site_half + ts * 16 + n;
            int y = y0 + (s >> 3), x = x0 + (s & 7);
            float pv[4];
#pragma unroll
            for (int r = 0; r < 4; ++r) {
                int oc = ocg * 64 + oc_half + toc * 16 + q * 4 + r;
                float v = fmaxf(acc[toc][ts][r] * (g[oc] * BN_INV) + be[oc], 0.f);
                out[((size_t)(b * COUT + oc) * HW + y) * HW + x] = v;
                if (POOL) {
                    float p = fmaxf(v, __shfl_xor(v, 1));
                    p = fmaxf(p, __shfl_xor(p, 8));
                    pv[r] = p;
                }
            }
            if (POOL && (n & 9) == 0) {
                ushort h[4], l[4];
#pragma unroll
                for (int r = 0; r < 4; ++r) fsplit(pv[r], h[r], l[r]);
                int ocb = ocg * 64 + oc_half + toc * 16 + q * 4;
                ushort* op = pooled
                    + (((size_t)b * (HW / 2) + (y >> 1)) * (HW / 2) + (x >> 1)) * (2 * COUT);
                uint2 uh, ul;
                uh.x = (uint)h[0] | ((uint)h[1] << 16);
                uh.y = (uint)h[2] | ((uint)h[3] << 16);
                ul.x = (uint)l[0] | ((uint)l[1] << 16);
                ul.y = (uint)l[2] | ((uint)l[3] << 16);
                *(uint2*)(op + ocb) = uh;
                *(uint2*)(op + COUT + ocb) = ul;
            }
        }
    }
}

// ---------------------------------------------------------------------------
// Quantum stage + BN + ReLU (fp32). In-place safe (per-block plane).
// Only the 10 rows with nonzero Z-mean are computed (popc==2 -> zm=0).
// ---------------------------------------------------------------------------
__global__ __launch_bounds__(256) void quantum_bn_relu(
    const float* __restrict__ e4,  // (8,256,32,32)
    const float* __restrict__ U,   // (256,16,16,2)
    const float* __restrict__ g5, const float* __restrict__ b5,
    float* __restrict__ out)       // (8,256,32,32)
{
    int blk = blockIdx.x;      // b*256 + c
    int c = blk & 255;
    __shared__ float sp[32][32];
    __shared__ __align__(16) float sU[512];

    int tid = threadIdx.x;
    const float4* plane4 = (const float4*)(e4 + (size_t)blk * 1024);
    ((float4*)sp)[tid] = plane4[tid];
    const float4* Usrc = (const float4*)(U + (size_t)c * 512);
    if (tid < 128) ((float4*)sU)[tid] = Usrc[tid];
    __syncthreads();

    float t[4][16];
    float inv2[4];
#pragma unroll
    for (int k = 0; k < 4; ++k) {
        int site = tid + 256 * k;
        int y = site >> 5, x = site & 31;
        float ss = 0.f;
#pragma unroll
        for (int i = 0; i < 4; ++i)
#pragma unroll
            for (int j = 0; j < 4; ++j) {
                int yy = y + i - 1, xx = x + j - 1;
                float v = (yy >= 0 && yy < 32 && xx >= 0 && xx < 32) ? sp[yy][xx] : 0.f;
                t[k][i * 4 + j] = v;
                ss += v * v;
            }
        float inv = 1.f / fmaxf(sqrtf(ss), 1e-12f);
        inv2[k] = inv * inv;
    }

    const int   RI[10] = {0, 1, 2, 4, 7, 8, 11, 13, 14, 15};
    const float ZM[10] = {1.f, .5f, .5f, .5f, -.5f, .5f, -.5f, -.5f, -.5f, -1.f};
    const float4* sU4 = (const float4*)sU;

    float s[4] = {0.f, 0.f, 0.f, 0.f};
#pragma unroll
    for (int ii = 0; ii < 10; ++ii) {
        int i = RI[ii];
        float re[4] = {0.f, 0.f, 0.f, 0.f};
        float im[4] = {0.f, 0.f, 0.f, 0.f};
#pragma unroll
        for (int jj = 0; jj < 8; ++jj) {
            float4 u = sU4[i * 8 + jj];
#pragma unroll
            for (int k = 0; k < 4; ++k) {
                re[k] += u.x * t[k][2 * jj];
                im[k] += u.y * t[k][2 * jj];
                re[k] += u.z * t[k][2 * jj + 1];
                im[k] += u.w * t[k][2 * jj + 1];
            }
        }
        float zm = ZM[ii];
#pragma unroll
        for (int k = 0; k < 4; ++k)
            s[k] += (re[k] * re[k] + im[k] * im[k]) * zm;
    }

    float sc = g5[c] * BN_INV, bi = b5[c];
#pragma unroll
    for (int k = 0; k < 4; ++k) {
        float q = (s[k] * inv2[k] + 1.f) * 0.5f;
        float o = fmaxf(q * sc + bi, 0.f);
        out[(size_t)blk * 1024 + tid + 256 * k] = o;
    }
}

// ---------------------------------------------------------------------------
extern "C" void kernel_launch(void* const* d_in, const int* in_sizes, int n_in,
                              void* d_out, int out_size, void* d_ws, size_t ws_size,
                              hipStream_t stream)
{
    const float* x   = (const float*)d_in[0];
    const float* w1  = (const float*)d_in[1];
    const float* g1  = (const float*)d_in[2];
    const float* b1  = (const float*)d_in[3];
    const float* w2  = (const float*)d_in[4];
    const float* g2  = (const float*)d_in[5];
    const float* b2  = (const float*)d_in[6];
    const float* w3  = (const float*)d_in[7];
    const float* g3  = (const float*)d_in[8];
    const float* b3  = (const float*)d_in[9];
    const float* w4  = (const float*)d_in[10];
    const float* g4  = (const float*)d_in[11];
    const float* b4  = (const float*)d_in[12];
    const float* qw0 = (const float*)d_in[13];
    const float* qw1 = (const float*)d_in[14];
    const float* g5  = (const float*)d_in[15];
    const float* b5  = (const float*)d_in[16];

    float* out = (float*)d_out;
    float* e1  = out;                         // 8*32*256*256 = 16777216
    float* e2  = out + 16777216;              // 8*64*128*128 =  8388608
    float* e3  = out + 25165824;              // 8*128*64*64  =  4194304
    float* o4  = out + 29360128;              // 8*256*32*32  =  2097152

    float* ws = (float*)d_ws;
    // floats: Uw@0(131072) wb2@131072(18432) wb3@149504(73728)
    // wb4@223232(294912) pt1@518144(4194304) pt2@4712448(2097152)
    // pt3 aliases pt1 (dead after conv2). Peak ~27.2 MB.
    float*  Uw  = ws;
    ushort* wb2 = (ushort*)(ws + 131072);
    ushort* wb3 = (ushort*)(ws + 149504);
    ushort* wb4 = (ushort*)(ws + 223232);
    ushort* pt1 = (ushort*)(ws + 518144);     // (8,128,128,64)
    ushort* pt2 = (ushort*)(ws + 4712448);    // (8,64,64,128)
    ushort* pt3 = (ushort*)(ws + 518144);     // (8,32,32,256), aliases pt1

    prep_kernel<<<1528, 256, 0, stream>>>(qw0, qw1, Uw, w2, wb2, w3, wb3, w4, wb4);

    conv1_bn_relu_pool<<<8 * 256, 256, 0, stream>>>(x, w1, g1, b1, e1, pt1);

    conv3x3_mfma_split<32, 64, 128, true><<<2048, 256, 0, stream>>>(pt1, wb2, g2, b2, e2, pt2);

    conv3x3_mfma_split<64, 128, 64, true><<<1024, 256, 0, stream>>>(pt2, wb3, g3, b3, e3, pt3);

    conv3x3_mfma_split<128, 256, 32, false><<<512, 256, 0, stream>>>(pt3, wb4, g4, b4, o4, nullptr);

    quantum_bn_relu<<<2048, 256, 0, stream>>>(o4, Uw, g5, b5, o4);
}

// Round 7
// 296.995 us; speedup vs baseline: 3.3384x; 1.0490x over previous
//
#include <hip/hip_runtime.h>
#include <cstdint>
#include <cstddef>

#define BN_INV 0.9999950000374997f  /* 1/sqrt(1+1e-5) */

typedef __attribute__((ext_vector_type(8))) _Float16 h8v;
typedef __attribute__((ext_vector_type(4))) float f4v;

// split v = hi + lo, both fp16; residual <= 2^-22 * |v|
__device__ __forceinline__ void fsplit(float v, ushort& h, ushort& l) {
    _Float16 hh = (_Float16)v;
    _Float16 ll = (_Float16)(v - (float)hh);
    h = __builtin_bit_cast(ushort, hh);
    l = __builtin_bit_cast(ushort, ll);
}

// ---------------------------------------------------------------------------
// Repack helper: (O,I,3,3) fp32 -> split fp16 hi/lo planes, A-frag order.
// dst[(ocg*NCH+chunk)*2*18432 + comp*18432 + tap*2048 + q*512 + oc*8 + j],
// ic = chunk*32 + q*8 + j
// ---------------------------------------------------------------------------
__device__ __forceinline__ void repack_one(
    const float* __restrict__ w, ushort* __restrict__ dst, int CIN, int i)
{
    int ocf = i / (CIN * 9);
    int r = i % (CIN * 9);
    int ic = r / 9;
    int tap = r % 9;
    int ocg = ocf >> 6, oc = ocf & 63;
    int chunk = ic >> 5, q = (ic >> 3) & 3, j = ic & 7;
    int nch = CIN >> 5;
    ushort h, l;
    fsplit(w[i], h, l);
    size_t base = (size_t)((ocg * nch + chunk) * 2) * 18432
                + (size_t)tap * 2048 + q * 512 + oc * 8 + j;
    dst[base] = h;
    dst[base + 18432] = l;
}

// ---------------------------------------------------------------------------
// Fused prep + conv1.
// Blocks 0..15: build U. 16..1527: repack w2/w3/w4.
// Blocks 1528..3575: conv1 (1->32, 256x256) + BN + ReLU -> e1 fp32,
// fused 2x2 pool -> split fp16 channel-last pt1 [b][128][128][hi32|lo32].
// ---------------------------------------------------------------------------
__global__ __launch_bounds__(256) void prep_conv1_kernel(
    const float* __restrict__ w0, const float* __restrict__ w1,
    float* __restrict__ U,
    const float* __restrict__ w2, ushort* __restrict__ wb2,
    const float* __restrict__ w3, ushort* __restrict__ wb3,
    const float* __restrict__ w4, ushort* __restrict__ wb4,
    const float* __restrict__ x, const float* __restrict__ wt,
    const float* __restrict__ g, const float* __restrict__ be,
    float* __restrict__ out, ushort* __restrict__ pooled)
{
    __shared__ float s_in[18][18];
    __shared__ float s_w[288];

    int blk = blockIdx.x;
    int tid = threadIdx.x;

    if (blk < 1528) {
        if (blk >= 376)      { repack_one(w4, wb4, 128, (blk - 376) * 256 + tid); return; }
        if (blk >= 88)       { repack_one(w3, wb3,  64, (blk -  88) * 256 + tid); return; }
        if (blk >= 16)       { repack_one(w2, wb2,  32, (blk -  16) * 256 + tid); return; }

        int idx = blk * 256 + tid;  // = c*16 + r
        int c = idx >> 4, r = idx & 15;
        float gr[4][2][2], gi[4][2][2];
        const float inv_sq2 = 0.70710678118654752f;
#pragma unroll
        for (int w = 0; w < 4; ++w) {
            float ty = w0[c * 2 + (w & 1)];
            float tz = w1[c * 2 + (w & 1)];
            float cy = cosf(0.5f * ty), sy = sinf(0.5f * ty);
            float cz = cosf(0.5f * tz), sz = sinf(0.5f * tz);
            float r00 = (cy - sy) * inv_sq2, r01 = (cy + sy) * inv_sq2;
            float r10 = (cy + sy) * inv_sq2, r11 = (sy - cy) * inv_sq2;
            gr[w][0][0] = cz * r00; gi[w][0][0] = -sz * r00;
            gr[w][0][1] = cz * r01; gi[w][0][1] = -sz * r01;
            gr[w][1][0] = cz * r10; gi[w][1][0] =  sz * r10;
            gr[w][1][1] = cz * r11; gi[w][1][1] =  sz * r11;
        }
        const int PTOT[16] = {0,13,3,14,6,11,5,8,12,1,15,2,10,7,9,4};
        int rp = PTOT[r];
        float* Uo = U + (size_t)c * 512 + r * 32;
#pragma unroll
        for (int cc = 0; cc < 16; ++cc) {
            float pr = 1.f, pi = 0.f;
#pragma unroll
            for (int w = 0; w < 4; ++w) {
                int ib = (rp >> (3 - w)) & 1, jb = (cc >> (3 - w)) & 1;
                float ar = gr[w][ib][jb], ai = gi[w][ib][jb];
                float nr = pr * ar - pi * ai;
                float ni = pr * ai + pi * ar;
                pr = nr; pi = ni;
            }
            Uo[cc * 2 + 0] = pr;
            Uo[cc * 2 + 1] = pi;
        }
        return;
    }

    // ---- conv1 path ----
    int bid = blk - 1528;
    int tile = bid & 255;
    int b = bid >> 8;
    int tx0 = (tile & 15) * 16, ty0 = (tile >> 4) * 16;

    for (int i = tid; i < 288; i += 256) s_w[i] = wt[i];
    for (int i = tid; i < 18 * 18; i += 256) {
        int yy = i / 18, xx = i % 18;
        int gy = ty0 + yy - 1, gx = tx0 + xx - 1;
        float v = 0.f;
        if (gy >= 0 && gy < 256 && gx >= 0 && gx < 256)
            v = x[(size_t)b * 65536 + gy * 256 + gx];
        s_in[yy][xx] = v;
    }
    __syncthreads();

    int px = tid & 15, py = tid >> 4;
    float t[3][3];
#pragma unroll
    for (int i = 0; i < 3; ++i)
#pragma unroll
        for (int j = 0; j < 3; ++j) t[i][j] = s_in[py + i][px + j];

    bool wr_pool = ((px & 1) == 0) && ((py & 1) == 0);
    ushort ph[32], pl[32];

    size_t obase = ((size_t)b * 32) * 65536 + (size_t)(ty0 + py) * 256 + (tx0 + px);
#pragma unroll 4
    for (int oc = 0; oc < 32; ++oc) {
        const float* wr = &s_w[oc * 9];
        float s = wr[0]*t[0][0] + wr[1]*t[0][1] + wr[2]*t[0][2]
                + wr[3]*t[1][0] + wr[4]*t[1][1] + wr[5]*t[1][2]
                + wr[6]*t[2][0] + wr[7]*t[2][1] + wr[8]*t[2][2];
        s = s * (g[oc] * BN_INV) + be[oc];
        s = fmaxf(s, 0.f);
        out[obase + (size_t)oc * 65536] = s;
        float p = fmaxf(s, __shfl_xor(s, 1));
        p = fmaxf(p, __shfl_xor(p, 16));
        fsplit(p, ph[oc], pl[oc]);
    }
    if (wr_pool) {
        ushort* op = pooled + (((size_t)b * 128 + ((ty0 + py) >> 1)) * 128 + ((tx0 + px) >> 1)) * 64;
#pragma unroll
        for (int k = 0; k < 4; ++k) {
            uint4 u;
            u.x = (uint)ph[8*k+0] | ((uint)ph[8*k+1] << 16);
            u.y = (uint)ph[8*k+2] | ((uint)ph[8*k+3] << 16);
            u.z = (uint)ph[8*k+4] | ((uint)ph[8*k+5] << 16);
            u.w = (uint)ph[8*k+6] | ((uint)ph[8*k+7] << 16);
            *(uint4*)(op + 8 * k) = u;
            uint4 v;
            v.x = (uint)pl[8*k+0] | ((uint)pl[8*k+1] << 16);
            v.y = (uint)pl[8*k+2] | ((uint)pl[8*k+3] << 16);
            v.z = (uint)pl[8*k+4] | ((uint)pl[8*k+5] << 16);
            v.w = (uint)pl[8*k+6] | ((uint)pl[8*k+7] << 16);
            *(uint4*)(op + 32 + 8 * k) = v;
        }
    }
}

// ---------------------------------------------------------------------------
// Split-fp16 MFMA implicit-GEMM 3x3 conv + BN + ReLU, optional fused pool.
// Tile: 64 oc x 128 sites (16 wide x 8 tall); 4 waves = 2 oc-halves x
// 2 site-groups (rows sg*4..sg*4+3). Per wave per tap: 4 global A-frag
// loads, 8 ds_read_b128 B-frags, 24 MFMA (2x the A-reuse of the 64-site
// tile). Weights direct-from-global (L2-hot). LDS = input halo only
// (180 pos x 72 ushorts = 25.9 KB). Tap loop unroll 3 to cap VGPRs.
// acc += Wh*Bh + Wh*Bl + Wl*Bh (err ~2^-22).
// ---------------------------------------------------------------------------
template <int CIN, int COUT, int HW, bool POOL>
__global__ __launch_bounds__(256) void conv3x3_mfma_split(
    const ushort* __restrict__ in,   // (8,HW,HW,2*CIN)
    const ushort* __restrict__ wb,   // packed split
    const float* __restrict__ g, const float* __restrict__ be,
    float* __restrict__ out,         // (8,COUT,HW,HW) fp32
    ushort* __restrict__ pooled)     // (8,HW/2,HW/2,2*COUT) if POOL
{
    constexpr int NCH = CIN / 32;
    constexpr int NTX = HW / 16;
    constexpr int NT = NTX * (HW / 8);
    constexpr int NOCG = COUT / 64;
    constexpr int PS = 72;

    __shared__ __align__(16) ushort s_in[180 * PS];  // 25920 B

    int bid = blockIdx.x;
    int tile = bid % NT;
    int rest = bid / NT;
    int ocg = rest % NOCG;
    int b = rest / NOCG;
    int x0 = (tile % NTX) * 16;
    int y0 = (tile / NTX) * 8;

    int tid = threadIdx.x;
    int wv = tid >> 6;
    int lane = tid & 63;
    int n = lane & 15;
    int q = lane >> 4;
    int oc_half = (wv & 1) * 32;
    int sg = wv >> 1;            // site-group: rows sg*4 .. sg*4+3

    int ib[4];
#pragma unroll
    for (int f = 0; f < 4; ++f)
        ib[f] = ((sg * 4 + f) * 18 + n) * PS + q * 8;
    int iwa0 = q * 512 + (oc_half + n) * 8;
    int iwa1 = q * 512 + (oc_half + 16 + n) * 8;

    const ushort* inb = in + (size_t)b * HW * HW * 2 * CIN;

    f4v acc[2][4];
#pragma unroll
    for (int a = 0; a < 2; ++a)
#pragma unroll
        for (int f = 0; f < 4; ++f) acc[a][f] = (f4v){0.f, 0.f, 0.f, 0.f};

    for (int ch = 0; ch < NCH; ++ch) {
        if (ch) __syncthreads();
        // stage input halo: 180 pos x {hi,lo} x 8 uint2-units (4 ic each)
#pragma unroll
        for (int it = 0; it < 12; ++it) {
            int i = tid + it * 256;
            if (i < 2880) {
                int pos = i >> 4;
                int r2 = i & 15;
                int comp = r2 >> 3;
                int u = r2 & 7;
                int py = pos / 18, px = pos % 18;
                int gy = y0 - 1 + py, gx = x0 - 1 + px;
                uint2 v; v.x = 0u; v.y = 0u;
                if (gy >= 0 && gy < HW && gx >= 0 && gx < HW)
                    v = *(const uint2*)(inb + ((size_t)gy * HW + gx) * (2 * CIN)
                                        + comp * CIN + ch * 32 + u * 4);
                *(uint2*)(&s_in[pos * PS + comp * 32 + u * 4]) = v;
            }
        }
        __syncthreads();

        const ushort* wc = wb + (size_t)((ocg * NCH + ch) * 2) * 18432;
#pragma unroll 3
        for (int tap = 0; tap < 9; ++tap) {
            const int toff = ((tap / 3) * 18 + (tap % 3)) * PS;
            const ushort* wt_ = wc + tap * 2048;
            h8v ah0 = *(const h8v*)(wt_ + iwa0);
            h8v ah1 = *(const h8v*)(wt_ + iwa1);
            h8v al0 = *(const h8v*)(wt_ + 18432 + iwa0);
            h8v al1 = *(const h8v*)(wt_ + 18432 + iwa1);
            h8v bh[4], bl[4];
#pragma unroll
            for (int f = 0; f < 4; ++f) {
                bh[f] = *(const h8v*)(&s_in[toff + ib[f]]);
                bl[f] = *(const h8v*)(&s_in[toff + ib[f] + 32]);
            }
#pragma unroll
            for (int f = 0; f < 4; ++f) {
                acc[0][f] = __builtin_amdgcn_mfma_f32_16x16x32_f16(ah0, bh[f], acc[0][f], 0, 0, 0);
                acc[1][f] = __builtin_amdgcn_mfma_f32_16x16x32_f16(ah1, bh[f], acc[1][f], 0, 0, 0);
            }
#pragma unroll
            for (int f = 0; f < 4; ++f) {
                acc[0][f] = __builtin_amdgcn_mfma_f32_16x16x32_f16(ah0, bl[f], acc[0][f], 0, 0, 0);
                acc[1][f] = __builtin_amdgcn_mfma_f32_16x16x32_f16(ah1, bl[f], acc[1][f], 0, 0, 0);
            }
#pragma unroll
            for (int f = 0; f < 4; ++f) {
                acc[0][f] = __builtin_amdgcn_mfma_f32_16x16x32_f16(al0, bh[f], acc[0][f], 0, 0, 0);
                acc[1][f] = __builtin_amdgcn_mfma_f32_16x16x32_f16(al1, bh[f], acc[1][f], 0, 0, 0);
            }
        }
    }

    // epilogue: D row = oc (q*4+r), col = site (n); y-row = sg*4+f, x = n
    float vr[2][4][4];
#pragma unroll
    for (int tf = 0; tf < 2; ++tf)
#pragma unroll
        for (int f = 0; f < 4; ++f) {
            int y = y0 + sg * 4 + f;
#pragma unroll
            for (int r = 0; r < 4; ++r) {
                int oc = ocg * 64 + oc_half + tf * 16 + q * 4 + r;
                float v = fmaxf(acc[tf][f][r] * (g[oc] * BN_INV) + be[oc], 0.f);
                vr[tf][f][r] = v;
                out[((size_t)(b * COUT + oc) * HW + y) * HW + (x0 + n)] = v;
            }
        }

    if (POOL) {
#pragma unroll
        for (int tf = 0; tf < 2; ++tf)
#pragma unroll
            for (int fp = 0; fp < 2; ++fp) {
                ushort h[4], l[4];
#pragma unroll
                for (int r = 0; r < 4; ++r) {
                    float p = fmaxf(vr[tf][2 * fp][r], vr[tf][2 * fp + 1][r]);
                    p = fmaxf(p, __shfl_xor(p, 1));
                    fsplit(p, h[r], l[r]);
                }
                if ((n & 1) == 0) {
                    int pyp = (y0 >> 1) + sg * 2 + fp;
                    int pxp = (x0 + n) >> 1;
                    int ocb = ocg * 64 + oc_half + tf * 16 + q * 4;
                    ushort* op = pooled
                        + (((size_t)b * (HW / 2) + pyp) * (HW / 2) + pxp) * (2 * COUT);
                    uint2 uh, ul;
                    uh.x = (uint)h[0] | ((uint)h[1] << 16);
                    uh.y = (uint)h[2] | ((uint)h[3] << 16);
                    ul.x = (uint)l[0] | ((uint)l[1] << 16);
                    ul.y = (uint)l[2] | ((uint)l[3] << 16);
                    *(uint2*)(op + ocb) = uh;
                    *(uint2*)(op + COUT + ocb) = ul;
                }
            }
    }
}

// ---------------------------------------------------------------------------
// Quantum stage + BN + ReLU (fp32). In-place safe (per-block plane).
// Only the 10 rows with nonzero Z-mean are computed (popc==2 -> zm=0).
// ---------------------------------------------------------------------------
__global__ __launch_bounds__(256) void quantum_bn_relu(
    const float* __restrict__ e4,  // (8,256,32,32)
    const float* __restrict__ U,   // (256,16,16,2)
    const float* __restrict__ g5, const float* __restrict__ b5,
    float* __restrict__ out)       // (8,256,32,32)
{
    int blk = blockIdx.x;      // b*256 + c
    int c = blk & 255;
    __shared__ float sp[32][32];
    __shared__ __align__(16) float sU[512];

    int tid = threadIdx.x;
    const float4* plane4 = (const float4*)(e4 + (size_t)blk * 1024);
    ((float4*)sp)[tid] = plane4[tid];
    const float4* Usrc = (const float4*)(U + (size_t)c * 512);
    if (tid < 128) ((float4*)sU)[tid] = Usrc[tid];
    __syncthreads();

    float t[4][16];
    float inv2[4];
#pragma unroll
    for (int k = 0; k < 4; ++k) {
        int site = tid + 256 * k;
        int y = site >> 5, x = site & 31;
        float ss = 0.f;
#pragma unroll
        for (int i = 0; i < 4; ++i)
#pragma unroll
            for (int j = 0; j < 4; ++j) {
                int yy = y + i - 1, xx = x + j - 1;
                float v = (yy >= 0 && yy < 32 && xx >= 0 && xx < 32) ? sp[yy][xx] : 0.f;
                t[k][i * 4 + j] = v;
                ss += v * v;
            }
        float inv = 1.f / fmaxf(sqrtf(ss), 1e-12f);
        inv2[k] = inv * inv;
    }

    const int   RI[10] = {0, 1, 2, 4, 7, 8, 11, 13, 14, 15};
    const float ZM[10] = {1.f, .5f, .5f, .5f, -.5f, .5f, -.5f, -.5f, -.5f, -1.f};
    const float4* sU4 = (const float4*)sU;

    float s[4] = {0.f, 0.f, 0.f, 0.f};
#pragma unroll
    for (int ii = 0; ii < 10; ++ii) {
        int i = RI[ii];
        float re[4] = {0.f, 0.f, 0.f, 0.f};
        float im[4] = {0.f, 0.f, 0.f, 0.f};
#pragma unroll
        for (int jj = 0; jj < 8; ++jj) {
            float4 u = sU4[i * 8 + jj];
#pragma unroll
            for (int k = 0; k < 4; ++k) {
                re[k] += u.x * t[k][2 * jj];
                im[k] += u.y * t[k][2 * jj];
                re[k] += u.z * t[k][2 * jj + 1];
                im[k] += u.w * t[k][2 * jj + 1];
            }
        }
        float zm = ZM[ii];
#pragma unroll
        for (int k = 0; k < 4; ++k)
            s[k] += (re[k] * re[k] + im[k] * im[k]) * zm;
    }

    float sc = g5[c] * BN_INV, bi = b5[c];
#pragma unroll
    for (int k = 0; k < 4; ++k) {
        float q = (s[k] * inv2[k] + 1.f) * 0.5f;
        float o = fmaxf(q * sc + bi, 0.f);
        out[(size_t)blk * 1024 + tid + 256 * k] = o;
    }
}

// ---------------------------------------------------------------------------
extern "C" void kernel_launch(void* const* d_in, const int* in_sizes, int n_in,
                              void* d_out, int out_size, void* d_ws, size_t ws_size,
                              hipStream_t stream)
{
    const float* x   = (const float*)d_in[0];
    const float* w1  = (const float*)d_in[1];
    const float* g1  = (const float*)d_in[2];
    const float* b1  = (const float*)d_in[3];
    const float* w2  = (const float*)d_in[4];
    const float* g2  = (const float*)d_in[5];
    const float* b2  = (const float*)d_in[6];
    const float* w3  = (const float*)d_in[7];
    const float* g3  = (const float*)d_in[8];
    const float* b3  = (const float*)d_in[9];
    const float* w4  = (const float*)d_in[10];
    const float* g4  = (const float*)d_in[11];
    const float* b4  = (const float*)d_in[12];
    const float* qw0 = (const float*)d_in[13];
    const float* qw1 = (const float*)d_in[14];
    const float* g5  = (const float*)d_in[15];
    const float* b5  = (const float*)d_in[16];

    float* out = (float*)d_out;
    float* e1  = out;                         // 8*32*256*256 = 16777216
    float* e2  = out + 16777216;              // 8*64*128*128 =  8388608
    float* e3  = out + 25165824;              // 8*128*64*64  =  4194304
    float* o4  = out + 29360128;              // 8*256*32*32  =  2097152

    float* ws = (float*)d_ws;
    // floats: Uw@0(131072) wb2@131072(18432) wb3@149504(73728)
    // wb4@223232(294912) pt1@518144(4194304) pt2@4712448(2097152)
    // pt3 aliases pt1 (dead after conv2). Peak ~27.2 MB.
    float*  Uw  = ws;
    ushort* wb2 = (ushort*)(ws + 131072);
    ushort* wb3 = (ushort*)(ws + 149504);
    ushort* wb4 = (ushort*)(ws + 223232);
    ushort* pt1 = (ushort*)(ws + 518144);     // (8,128,128,64)
    ushort* pt2 = (ushort*)(ws + 4712448);    // (8,64,64,128)
    ushort* pt3 = (ushort*)(ws + 518144);     // (8,32,32,256), aliases pt1

    prep_conv1_kernel<<<1528 + 2048, 256, 0, stream>>>(
        qw0, qw1, Uw, w2, wb2, w3, wb3, w4, wb4,
        x, w1, g1, b1, e1, pt1);

    conv3x3_mfma_split<32, 64, 128, true><<<1024, 256, 0, stream>>>(pt1, wb2, g2, b2, e2, pt2);

    conv3x3_mfma_split<64, 128, 64, true><<<512, 256, 0, stream>>>(pt2, wb3, g3, b3, e3, pt3);

    conv3x3_mfma_split<128, 256, 32, false><<<256, 256, 0, stream>>>(pt3, wb4, g4, b4, o4, nullptr);

    quantum_bn_relu<<<2048, 256, 0, stream>>>(o4, Uw, g5, b5, o4);
}